// Round 10
// baseline (561.972 us; speedup 1.0000x reference)
//
#include <hip/hip_runtime.h>
#include <hip/hip_bf16.h>
#include <cstdint>
#include <cstddef>

// ---------------------------------------------------------------------------
// EnhancedObj: visual/object attention block, bf16-MFMA implementation.
// Shapes (hardcoded): bs=8, F=64, obj=36, d=2048.
//   MO = 18432 object rows, MV = 512 visual rows, NOBJ = 2304.
// Round 10: k_cvt_bf16 eliminated -- the obj GEMM stages A directly from
// fp32 via registers (issue loads at iter start, vmcnt(0) after MFMA block,
// v_cvt_pk_bf16_f32 convert, ds_write_b128 into the swizzled layout,
// lgkmcnt(0), barrier). B staging (global_load_lds), frag reads, MFMA and
// the fused tanh/LN-partial epilogue unchanged from round 8/9.
// ---------------------------------------------------------------------------

typedef __attribute__((ext_vector_type(4))) float f32x4;
typedef __attribute__((ext_vector_type(4))) unsigned int u32x4;
typedef __attribute__((ext_vector_type(8))) short bf16x8;

#define DD 2048
#define BS 8
#define FF 64
#define NOBJ 2304
#define MO 18432
#define MV 512

__device__ __forceinline__ unsigned short f2bf(float f) {
  unsigned int u = __float_as_uint(f);
  u += 0x7fffu + ((u >> 16) & 1u);          // RTNE (inputs finite)
  return (unsigned short)(u >> 16);
}
__device__ __forceinline__ unsigned int pk2(float a, float b) {
  return (unsigned int)f2bf(a) | ((unsigned int)f2bf(b) << 16);
}
__device__ __forceinline__ float bf2f(unsigned short u) {
  return __uint_as_float((unsigned int)u << 16);
}
__device__ __forceinline__ unsigned int pkrn(float a, float b) {
  __hip_bfloat162 h = __float22bfloat162_rn(make_float2(a, b));  // v_cvt_pk_bf16_f32
  return *reinterpret_cast<unsigned int*>(&h);
}

typedef __attribute__((address_space(1))) const unsigned int gas_u32;
typedef __attribute__((address_space(3))) unsigned int las_u32;
__device__ __forceinline__ void gl_lds16(const void* g, void* l) {
  __builtin_amdgcn_global_load_lds((gas_u32*)g, (las_u32*)l, 16, 0, 0);
}

// --------------------------------------------------------------------------
// Both W[k][n] fp32 (2048x2048) -> Wt[n][k] bf16. 64x64 tiles via LDS.
// grid (32, 32, 2): z selects (W_v -> WvT) or (W_o -> WoT).
// --------------------------------------------------------------------------
__global__ __launch_bounds__(256) void k_wprep2(const float* __restrict__ Wv,
                                                const float* __restrict__ Wo,
                                                unsigned short* __restrict__ WvT,
                                                unsigned short* __restrict__ WoT) {
  __shared__ unsigned short sh[64][65];
  const float* W = blockIdx.z ? Wo : Wv;
  unsigned short* Wt = blockIdx.z ? WoT : WvT;
  const int t = threadIdx.x;
  const int kb = blockIdx.x * 64, nb = blockIdx.y * 64;
  {
    const int rk = t >> 2, seg = t & 3;
    const float* src = W + (size_t)(kb + rk) * DD + nb + seg * 16;
#pragma unroll
    for (int q = 0; q < 4; ++q) {
      f32x4 x = *(const f32x4*)(src + q * 4);
      sh[rk][seg * 16 + q * 4 + 0] = f2bf(x.x);
      sh[rk][seg * 16 + q * 4 + 1] = f2bf(x.y);
      sh[rk][seg * 16 + q * 4 + 2] = f2bf(x.z);
      sh[rk][seg * 16 + q * 4 + 3] = f2bf(x.w);
    }
  }
  __syncthreads();
  {
    const int nn = t >> 2, ks = t & 3;
    unsigned int o[8];
#pragma unroll
    for (int j = 0; j < 8; ++j)
      o[j] = (unsigned int)sh[ks * 16 + 2 * j][nn] |
             ((unsigned int)sh[ks * 16 + 2 * j + 1][nn] << 16);
    u32x4 p0 = {o[0], o[1], o[2], o[3]};
    u32x4 p1 = {o[4], o[5], o[6], o[7]};
    unsigned short* dst = Wt + (size_t)(nb + nn) * DD + kb + ks * 16;
    ((u32x4*)dst)[0] = p0;
    ((u32x4*)dst)[1] = p1;
  }
}

// --------------------------------------------------------------------------
// Obj GEMM fused: T[MO][2048] = bf16(tanh(A32@Bt^T + bias));
// part[row][32][2] = {sum, sumsq} of tanh over 64-col groups.
// BM=256 BN=128 BK=64, 512 thr = 8 waves (wm 0..3, wn 0..1), 64x64 out/wave.
// A is fp32 in HBM: reg-staged (8 f32x4 loads issued at iter start for tile
// kt+2; vmcnt(0) after MFMA; cvt_pk -> ds_write_b128 swizzled; lgkmcnt(0);
// barrier). B staged via global_load_lds into the same rotation.
// 3 LDS buffers rotate exactly as round 3/8/9.
// LDS: row-major, row r's 16B chunk at phys slot s holds logical
// k16 = s ^ (r&7). grid = (16, 72); XCD-bijective swizzle (1152 wgs).
// --------------------------------------------------------------------------
__global__ __launch_bounds__(512, 1) void k_gemm_bbf(const float* __restrict__ A32,
                                                     const unsigned short* __restrict__ Bt,
                                                     const float* __restrict__ bias,
                                                     unsigned short* __restrict__ T,
                                                     float* __restrict__ part) {
  // per buffer: A tile 256x64 (16384 e) + B tile 128x64 (8192 e) = 48 KiB
  __shared__ __align__(16) unsigned short lds[3 * 24576];
  const int tid = threadIdx.x;
  const int lane = tid & 63, wave = tid >> 6;
  const int r = lane & 15, g = lane >> 4;
  const int wm = wave >> 1, wn = wave & 1;

  // XCD-aware bijective remap (nwg = 1152, %8 == 0, per = 144)
  const int orig = blockIdx.y * 16 + blockIdx.x;
  const int lin = (orig & 7) * 144 + (orig >> 3);
  const int bm = (lin >> 4) * 256;
  const int bn = (lin & 15) * 128;

  // staging: thread covers 8-elem chunk c = q*512+tid -> row = c>>3, slot = c&7
  // physical slot holds logical k16 = slot ^ (row&7)  (XOR involution)
  const int srow = tid >> 3;                    // 0..63 (row within q-block)
  const int k16s = (tid & 7) ^ (srow & 7);
  const float* aSrc[4];
#pragma unroll
  for (int q = 0; q < 4; ++q)
    aSrc[q] = A32 + (size_t)(bm + q * 64 + srow) * DD + k16s * 8;
  const unsigned short* bSrc[2];
#pragma unroll
  for (int q = 0; q < 2; ++q)
    bSrc[q] = Bt + (size_t)(bn + q * 64 + srow) * DD + k16s * 8;

  f32x4 aR[4][2];  // in-flight A chunks (fp32), 32 VGPR

  auto stageIssue = [&](int buf, int kt) {
    const size_t ko = (size_t)kt * 64;
#pragma unroll
    for (int q = 0; q < 4; ++q) {
      aR[q][0] = ((const f32x4*)(aSrc[q] + ko))[0];
      aR[q][1] = ((const f32x4*)(aSrc[q] + ko))[1];
    }
    unsigned short* bb = lds + buf * 24576 + 16384;
#pragma unroll
    for (int q = 0; q < 2; ++q)
      gl_lds16(bSrc[q] + ko, bb + ((q * 512 + tid) << 3));
  };
  auto stageWrite = [&](int buf) {
    unsigned short* ab = lds + buf * 24576;
#pragma unroll
    for (int q = 0; q < 4; ++q) {
      u32x4 w = {pkrn(aR[q][0].x, aR[q][0].y), pkrn(aR[q][0].z, aR[q][0].w),
                 pkrn(aR[q][1].x, aR[q][1].y), pkrn(aR[q][1].z, aR[q][1].w)};
      *(u32x4*)(ab + ((q * 512 + tid) << 3)) = w;
    }
  };

  // frag-read swizzled slot offsets (elements): slot = (kk*4+g) ^ (r&7)
  const int rs = r & 7;
  const int sa0 = ((0 + g) ^ rs) * 8;
  const int sa1 = ((4 + g) ^ rs) * 8;
  const int arow0 = wm * 64 + r;
  const int brow0 = wn * 64 + r;

  f32x4 acc[4][4] = {};
  stageIssue(0, 0);
  asm volatile("s_waitcnt vmcnt(0)" ::: "memory");
  stageWrite(0);
  stageIssue(1, 1);
  asm volatile("s_waitcnt vmcnt(0)" ::: "memory");
  stageWrite(1);
  asm volatile("s_waitcnt lgkmcnt(0)" ::: "memory");
  __builtin_amdgcn_s_barrier();

  for (int kt = 0; kt < DD / 64; ++kt) {
    const int cur = kt % 3;
    const bool st = (kt + 2 < DD / 64);
    if (st) stageIssue((kt + 2) % 3, kt + 2);
    const unsigned short* ab = lds + cur * 24576;
    const unsigned short* bb = ab + 16384;
    bf16x8 af[4][2], bfr[4][2];
#pragma unroll
    for (int mi = 0; mi < 4; ++mi) {
      const int ro = (arow0 + mi * 16) * 64;
      af[mi][0] = *(const bf16x8*)(ab + ro + sa0);
      af[mi][1] = *(const bf16x8*)(ab + ro + sa1);
    }
#pragma unroll
    for (int ni = 0; ni < 4; ++ni) {
      const int ro = (brow0 + ni * 16) * 64;
      bfr[ni][0] = *(const bf16x8*)(bb + ro + sa0);
      bfr[ni][1] = *(const bf16x8*)(bb + ro + sa1);
    }
    __builtin_amdgcn_s_setprio(1);
#pragma unroll
    for (int mi = 0; mi < 4; ++mi)
#pragma unroll
      for (int ni = 0; ni < 4; ++ni) {
        acc[mi][ni] = __builtin_amdgcn_mfma_f32_16x16x32_bf16(af[mi][0], bfr[ni][0], acc[mi][ni], 0, 0, 0);
        acc[mi][ni] = __builtin_amdgcn_mfma_f32_16x16x32_bf16(af[mi][1], bfr[ni][1], acc[mi][ni], 0, 0, 0);
      }
    __builtin_amdgcn_s_setprio(0);
    // All outstanding VMEM was issued >= one full compute step ago -> free.
    asm volatile("s_waitcnt vmcnt(0)" ::: "memory");
    if (st) stageWrite((kt + 2) % 3);
    asm volatile("s_waitcnt lgkmcnt(0)" ::: "memory");
    __builtin_amdgcn_s_barrier();
  }

  // ---- fused epilogue: bias + tanh -> bf16 T, per-row partial LN sums ----
  float bv[4];
#pragma unroll
  for (int ni = 0; ni < 4; ++ni) bv[ni] = bias[bn + wn * 64 + ni * 16 + r];
  const int slot = ((lin & 15) << 1) + wn;  // 32 col-groups of 64
#pragma unroll
  for (int mi = 0; mi < 4; ++mi) {
#pragma unroll
    for (int i2 = 0; i2 < 4; ++i2) {
      const int row = bm + wm * 64 + mi * 16 + g * 4 + i2;
      unsigned short* trow = T + (size_t)row * DD + bn + wn * 64 + r;
      float s1 = 0.f, s2 = 0.f;
#pragma unroll
      for (int ni = 0; ni < 4; ++ni) {
        const float tv = tanhf(acc[mi][ni][i2] + bv[ni]);
        trow[ni * 16] = f2bf(tv);
        s1 += tv;
        s2 += tv * tv;
      }
#pragma unroll
      for (int m = 1; m < 16; m <<= 1) {
        s1 += __shfl_xor(s1, m, 64);
        s2 += __shfl_xor(s2, m, 64);
      }
      if (r == 0) {
        float2 p2 = make_float2(s1, s2);
        *(float2*)(part + (size_t)row * 64 + slot * 2) = p2;
      }
    }
  }
}

// --------------------------------------------------------------------------
// part[row][32][2] -> stats[row] = (mean, rstd). One 32-lane group per row.
// grid = MO/8, block 256.
// --------------------------------------------------------------------------
__global__ __launch_bounds__(256) void k_stats(const float* __restrict__ part,
                                               float2* __restrict__ stats) {
  const int t = threadIdx.x;
  const int row = blockIdx.x * 8 + (t >> 5);
  const int i = t & 31;
  float2 p = ((const float2*)(part + (size_t)row * 64))[i];
  float s1 = p.x, s2 = p.y;
#pragma unroll
  for (int m = 1; m < 32; m <<= 1) {
    s1 += __shfl_xor(s1, m, 64);
    s2 += __shfl_xor(s2, m, 64);
  }
  if (i == 0) {
    const float mean = s1 * (1.0f / DD);
    const float var = s2 * (1.0f / DD) - mean * mean;
    stats[row] = make_float2(mean, rsqrtf(var + 1e-5f));
  }
}

// --------------------------------------------------------------------------
// Fused LN + dual-layout write: o = (T - mean)*rstd*g + b (bf16);
// writes oe[b][n][d] (row-major) AND oeT[b][d][n] (LDS transpose).
// grid (36, 32, 8), block 256.
// --------------------------------------------------------------------------
__global__ __launch_bounds__(256) void k_lnT(const unsigned short* __restrict__ T,
                                             const float2* __restrict__ stats,
                                             const float* __restrict__ gw,
                                             const float* __restrict__ bw,
                                             unsigned short* __restrict__ oe,
                                             unsigned short* __restrict__ oeT) {
  __shared__ unsigned short sh[64][65];
  const int t = threadIdx.x;
  const int b = blockIdx.z, nt = blockIdx.x, dt = blockIdx.y;
  {
    const int nn = t >> 2, seg = t & 3;
    const int row = b * NOBJ + nt * 64 + nn;
    const size_t base = (size_t)row * DD + dt * 64 + seg * 16;
    u32x4 x0 = ((const u32x4*)(T + base))[0];
    u32x4 x1 = ((const u32x4*)(T + base))[1];
    const float2 st = stats[row];
    const float* gp = gw + dt * 64 + seg * 16;
    const float* bp = bw + dt * 64 + seg * 16;
    f32x4 gq[4], bq[4];
#pragma unroll
    for (int q = 0; q < 4; ++q) {
      gq[q] = ((const f32x4*)gp)[q];
      bq[q] = ((const f32x4*)bp)[q];
    }
    const unsigned short* px0 = (const unsigned short*)&x0;
    const unsigned short* px1 = (const unsigned short*)&x1;
    unsigned short ov[16];
#pragma unroll
    for (int j = 0; j < 8; ++j) {
      const float v = bf2f(px0[j]);
      ov[j] = f2bf((v - st.x) * st.y * gq[j >> 2][j & 3] + bq[j >> 2][j & 3]);
    }
#pragma unroll
    for (int j = 0; j < 8; ++j) {
      const float v = bf2f(px1[j]);
      ov[8 + j] = f2bf((v - st.x) * st.y * gq[2 + (j >> 2)][j & 3] + bq[2 + (j >> 2)][j & 3]);
    }
    u32x4 o0 = {(unsigned int)ov[0] | ((unsigned int)ov[1] << 16),
                (unsigned int)ov[2] | ((unsigned int)ov[3] << 16),
                (unsigned int)ov[4] | ((unsigned int)ov[5] << 16),
                (unsigned int)ov[6] | ((unsigned int)ov[7] << 16)};
    u32x4 o1 = {(unsigned int)ov[8] | ((unsigned int)ov[9] << 16),
                (unsigned int)ov[10] | ((unsigned int)ov[11] << 16),
                (unsigned int)ov[12] | ((unsigned int)ov[13] << 16),
                (unsigned int)ov[14] | ((unsigned int)ov[15] << 16)};
    ((u32x4*)(oe + base))[0] = o0;
    ((u32x4*)(oe + base))[1] = o1;
#pragma unroll
    for (int j = 0; j < 16; ++j) sh[nn][seg * 16 + j] = ov[j];
  }
  __syncthreads();
  {
    const int dd = t >> 2, ns = t & 3;
    unsigned int o[8];
#pragma unroll
    for (int j = 0; j < 8; ++j)
      o[j] = (unsigned int)sh[ns * 16 + 2 * j][dd] |
             ((unsigned int)sh[ns * 16 + 2 * j + 1][dd] << 16);
    u32x4 p0 = {o[0], o[1], o[2], o[3]};
    u32x4 p1 = {o[4], o[5], o[6], o[7]};
    unsigned short* dst = oeT + ((size_t)b * DD + dt * 64 + dd) * NOBJ + nt * 64 + ns * 16;
    ((u32x4*)dst)[0] = p0;
    ((u32x4*)dst)[1] = p1;
  }
}

// --------------------------------------------------------------------------
// Y[M][2048] = X[M][2048](fp32) @ W + bias (inline convert). Visual branch.
// --------------------------------------------------------------------------
__global__ __launch_bounds__(256) void k_gemm_xw(const float* __restrict__ X,
                                                 const unsigned short* __restrict__ Wt,
                                                 const float* __restrict__ bias,
                                                 float* __restrict__ Y) {
  __shared__ __align__(16) unsigned short As[128 * 32];
  __shared__ __align__(16) unsigned short Bs[128 * 32];
  const int t = threadIdx.x;
  const int lane = t & 63, wave = t >> 6;
  const int r = lane & 15, g = lane >> 4;
  const int wm = wave >> 1, wn = wave & 1;
  const int bm = blockIdx.y * 128, bn = blockIdx.x * 128;
  const int arow = t >> 1, ah = t & 1;
  f32x4 acc[4][4] = {};
  const float* aptr = X + (size_t)(bm + arow) * DD + ah * 16;
  const unsigned short* bptr = Wt + (size_t)(bn + arow) * DD + ah * 16;
  for (int kt = 0; kt < DD / 32; ++kt) {
    const int kb = kt * 32;
    f32x4 a0 = *(const f32x4*)(aptr + kb);
    f32x4 a1 = *(const f32x4*)(aptr + kb + 4);
    f32x4 a2 = *(const f32x4*)(aptr + kb + 8);
    f32x4 a3 = *(const f32x4*)(aptr + kb + 12);
    u32x4 b0 = *(const u32x4*)(bptr + kb);
    u32x4 b1 = *(const u32x4*)(bptr + kb + 8);
    __syncthreads();
    u32x4 p0 = {pk2(a0.x, a0.y), pk2(a0.z, a0.w), pk2(a1.x, a1.y), pk2(a1.z, a1.w)};
    u32x4 p1 = {pk2(a2.x, a2.y), pk2(a2.z, a2.w), pk2(a3.x, a3.y), pk2(a3.z, a3.w)};
    ((u32x4*)As)[arow * 4 + ah * 2 + 0] = p0;
    ((u32x4*)As)[arow * 4 + ah * 2 + 1] = p1;
    ((u32x4*)Bs)[arow * 4 + ah * 2 + 0] = b0;
    ((u32x4*)Bs)[arow * 4 + ah * 2 + 1] = b1;
    __syncthreads();
    bf16x8 af[4], bfr[4];
#pragma unroll
    for (int m = 0; m < 4; ++m) af[m] = ((const bf16x8*)As)[(wm * 64 + m * 16 + r) * 4 + g];
#pragma unroll
    for (int n = 0; n < 4; ++n) bfr[n] = ((const bf16x8*)Bs)[(wn * 64 + n * 16 + r) * 4 + g];
#pragma unroll
    for (int m = 0; m < 4; ++m)
#pragma unroll
      for (int n = 0; n < 4; ++n)
        acc[m][n] = __builtin_amdgcn_mfma_f32_16x16x32_bf16(af[m], bfr[n], acc[m][n], 0, 0, 0);
  }
#pragma unroll
  for (int m = 0; m < 4; ++m) {
    const int row0 = bm + wm * 64 + m * 16 + g * 4;
#pragma unroll
    for (int n = 0; n < 4; ++n) {
      const int col = bn + wn * 64 + n * 16 + r;
      const float bvx = bias[col];
#pragma unroll
      for (int i = 0; i < 4; ++i)
        Y[(size_t)(row0 + i) * DD + col] = acc[m][n][i] + bvx;
    }
  }
}

// --------------------------------------------------------------------------
// Row-wise: t = tanh(Y[row] (+ Y2[row])); LN(t)*g+b -> optional bf16 / fp32.
// --------------------------------------------------------------------------
__global__ __launch_bounds__(256) void k_ep_ln(const float* __restrict__ Y,
                                               const float* __restrict__ Y2,
                                               const float* __restrict__ gw,
                                               const float* __restrict__ bw,
                                               unsigned short* __restrict__ obf,
                                               float* __restrict__ of32) {
  const int row = blockIdx.x, t = threadIdx.x;
  const size_t base = (size_t)row * DD + t * 8;
  f32x4 v0 = ((const f32x4*)(Y + base))[0];
  f32x4 v1 = ((const f32x4*)(Y + base))[1];
  if (Y2 != nullptr) {
    v0 += ((const f32x4*)(Y2 + base))[0];
    v1 += ((const f32x4*)(Y2 + base))[1];
  }
  float tv[8];
#pragma unroll
  for (int j = 0; j < 4; ++j) {
    tv[j] = tanhf(v0[j]);
    tv[4 + j] = tanhf(v1[j]);
  }
  float s1 = 0.f, s2 = 0.f;
#pragma unroll
  for (int j = 0; j < 8; ++j) {
    s1 += tv[j];
    s2 += tv[j] * tv[j];
  }
#pragma unroll
  for (int m = 1; m < 64; m <<= 1) {
    s1 += __shfl_xor(s1, m, 64);
    s2 += __shfl_xor(s2, m, 64);
  }
  __shared__ float r1[4], r2[4];
  const int wave = t >> 6;
  if ((t & 63) == 0) {
    r1[wave] = s1;
    r2[wave] = s2;
  }
  __syncthreads();
  const float S1 = r1[0] + r1[1] + r1[2] + r1[3];
  const float S2 = r2[0] + r2[1] + r2[2] + r2[3];
  const float mean = S1 * (1.0f / DD);
  const float var = S2 * (1.0f / DD) - mean * mean;
  const float rstd = rsqrtf(var + 1e-5f);
  f32x4 g0 = ((const f32x4*)(gw + t * 8))[0], g1 = ((const f32x4*)(gw + t * 8))[1];
  f32x4 bb0 = ((const f32x4*)(bw + t * 8))[0], bb1 = ((const f32x4*)(bw + t * 8))[1];
  float o[8];
#pragma unroll
  for (int j = 0; j < 4; ++j) {
    o[j] = (tv[j] - mean) * rstd * g0[j] + bb0[j];
    o[4 + j] = (tv[4 + j] - mean) * rstd * g1[j] + bb1[j];
  }
  if (obf != nullptr) {
    u32x4 p = {pk2(o[0], o[1]), pk2(o[2], o[3]), pk2(o[4], o[5]), pk2(o[6], o[7])};
    *((u32x4*)(obf + base)) = p;
  }
  if (of32 != nullptr) {
    f32x4 w0 = {o[0], o[1], o[2], o[3]}, w1 = {o[4], o[5], o[6], o[7]};
    ((f32x4*)(of32 + base))[0] = w0;
    ((f32x4*)(of32 + base))[1] = w1;
  }
}

// --------------------------------------------------------------------------
// adjT[b][f][n] = (oe[b][n][:] . ve[b][f][:]) / sqrt(2048).
// BM=64(n), 256 thr 4 waves. grid (36, 8) = 288 blocks.
// --------------------------------------------------------------------------
__global__ __launch_bounds__(256) void k_gemm_adj(const unsigned short* __restrict__ oe,
                                                  const unsigned short* __restrict__ veb,
                                                  float* __restrict__ adjT) {
  __shared__ __align__(16) unsigned short As[64 * 32];
  __shared__ __align__(16) unsigned short Bs[64 * 32];
  const int t = threadIdx.x;
  const int lane = t & 63, wave = t >> 6;
  const int r = lane & 15, g = lane >> 4;
  const int wm = wave >> 1, wn = wave & 1;
  const int b = blockIdx.y, bm = blockIdx.x * 64;
  const int arow = t >> 2, aseg = t & 3;
  f32x4 acc[2][2] = {};
  const unsigned short* aptr = oe + ((size_t)b * NOBJ + bm + arow) * DD + aseg * 8;
  const unsigned short* bptr = veb + ((size_t)b * FF + arow) * DD + aseg * 8;
  for (int kt = 0; kt < DD / 32; ++kt) {
    const int kb = kt * 32;
    u32x4 a0 = *(const u32x4*)(aptr + kb);
    u32x4 bvx = *(const u32x4*)(bptr + kb);
    __syncthreads();
    ((u32x4*)As)[arow * 4 + aseg] = a0;
    ((u32x4*)Bs)[arow * 4 + aseg] = bvx;
    __syncthreads();
    bf16x8 af[2], bfr[2];
#pragma unroll
    for (int m = 0; m < 2; ++m) af[m] = ((const bf16x8*)As)[(wm * 32 + m * 16 + r) * 4 + g];
#pragma unroll
    for (int n = 0; n < 2; ++n) bfr[n] = ((const bf16x8*)Bs)[(wn * 32 + n * 16 + r) * 4 + g];
#pragma unroll
    for (int m = 0; m < 2; ++m)
#pragma unroll
      for (int n = 0; n < 2; ++n)
        acc[m][n] = __builtin_amdgcn_mfma_f32_16x16x32_bf16(af[m], bfr[n], acc[m][n], 0, 0, 0);
  }
  const float scale = 0.02209708691207961f;  // 1/sqrt(2048)
#pragma unroll
  for (int m = 0; m < 2; ++m)
#pragma unroll
    for (int n = 0; n < 2; ++n) {
      const int f = wn * 32 + n * 16 + r;
      const int n0 = bm + wm * 32 + m * 16 + g * 4;
      f32x4 v = acc[m][n];
      v *= scale;
      *(f32x4*)(adjT + ((size_t)b * FF + f) * NOBJ + n0) = v;
    }
}

// --------------------------------------------------------------------------
// Row softmax over 2304 (rows of adjT), write bf16. grid = 512 rows.
// --------------------------------------------------------------------------
__global__ __launch_bounds__(256) void k_smax(const float* __restrict__ adjT,
                                              unsigned short* __restrict__ out) {
  const int t = threadIdx.x;
  const size_t base = (size_t)blockIdx.x * NOBJ;
  float v[9];
#pragma unroll
  for (int j = 0; j < 9; ++j) v[j] = adjT[base + t + j * 256];
  float m = v[0];
#pragma unroll
  for (int j = 1; j < 9; ++j) m = fmaxf(m, v[j]);
#pragma unroll
  for (int s = 1; s < 64; s <<= 1) m = fmaxf(m, __shfl_xor(m, s, 64));
  __shared__ float rm[4], rs[4];
  const int wave = t >> 6;
  if ((t & 63) == 0) rm[wave] = m;
  __syncthreads();
  m = fmaxf(fmaxf(rm[0], rm[1]), fmaxf(rm[2], rm[3]));
  float e[9];
  float s = 0.f;
#pragma unroll
  for (int j = 0; j < 9; ++j) {
    e[j] = __expf(v[j] - m);
    s += e[j];
  }
#pragma unroll
  for (int q = 1; q < 64; q <<= 1) s += __shfl_xor(s, q, 64);
  if ((t & 63) == 0) rs[wave] = s;
  __syncthreads();
  const float S = rs[0] + rs[1] + rs[2] + rs[3];
  const float inv = 1.0f / S;
#pragma unroll
  for (int j = 0; j < 9; ++j) out[base + t + j * 256] = f2bf(e[j] * inv);
}

// --------------------------------------------------------------------------
// agg[b][f][d] = sum_n adj_sm[b][f][n] * oeT[b][d][n].
// BN=64(d), 256 thr 4 waves. grid (32, 8) = 256 blocks.
// --------------------------------------------------------------------------
__global__ __launch_bounds__(256) void k_gemm_agg(const unsigned short* __restrict__ adjsm,
                                                  const unsigned short* __restrict__ oeT,
                                                  float* __restrict__ agg) {
  __shared__ __align__(16) unsigned short As[64 * 32];
  __shared__ __align__(16) unsigned short Bs[64 * 32];
  const int t = threadIdx.x;
  const int lane = t & 63, wave = t >> 6;
  const int r = lane & 15, g = lane >> 4;
  const int wm = wave >> 1, wn = wave & 1;
  const int b = blockIdx.y, bn = blockIdx.x * 64;
  const int arow = t >> 2, aseg = t & 3;
  f32x4 acc[2][2] = {};
  const unsigned short* aptr = adjsm + ((size_t)b * FF + arow) * NOBJ + aseg * 8;
  const unsigned short* bptr = oeT + ((size_t)b * DD + bn + arow) * NOBJ + aseg * 8;
  for (int kt = 0; kt < NOBJ / 32; ++kt) {
    const int kb = kt * 32;
    u32x4 av = *(const u32x4*)(aptr + kb);
    u32x4 bvx = *(const u32x4*)(bptr + kb);
    __syncthreads();
    ((u32x4*)As)[arow * 4 + aseg] = av;
    ((u32x4*)Bs)[arow * 4 + aseg] = bvx;
    __syncthreads();
    bf16x8 af[2], bfr[2];
#pragma unroll
    for (int m = 0; m < 2; ++m) af[m] = ((const bf16x8*)As)[(wm * 32 + m * 16 + r) * 4 + g];
#pragma unroll
    for (int n = 0; n < 2; ++n) bfr[n] = ((const bf16x8*)Bs)[(wn * 32 + n * 16 + r) * 4 + g];
#pragma unroll
    for (int m = 0; m < 2; ++m)
#pragma unroll
      for (int n = 0; n < 2; ++n)
        acc[m][n] = __builtin_amdgcn_mfma_f32_16x16x32_bf16(af[m], bfr[n], acc[m][n], 0, 0, 0);
  }
#pragma unroll
  for (int m = 0; m < 2; ++m)
#pragma unroll
    for (int n = 0; n < 2; ++n) {
      const int d = bn + wn * 32 + n * 16 + r;
#pragma unroll
      for (int i = 0; i < 4; ++i) {
        const int f = wm * 32 + m * 16 + g * 4 + i;
        agg[((size_t)b * FF + f) * DD + d] = acc[m][n][i];
      }
    }
}

// --------------------------------------------------------------------------

extern "C" void kernel_launch(void* const* d_in, const int* in_sizes, int n_in,
                              void* d_out, int out_size, void* d_ws, size_t ws_size,
                              hipStream_t stream) {
  (void)in_sizes; (void)n_in; (void)out_size;
  const float* visual = (const float*)d_in[0];
  const float* obj    = (const float*)d_in[1];
  const float* W_v    = (const float*)d_in[2];
  const float* b_v    = (const float*)d_in[3];
  const float* W_o    = (const float*)d_in[4];
  const float* b_o    = (const float*)d_in[5];
  const float* ln_v_g = (const float*)d_in[6];
  const float* ln_v_b = (const float*)d_in[7];
  const float* ln_o_g = (const float*)d_in[8];
  const float* ln_o_b = (const float*)d_in[9];
  const float* ln_ov_g = (const float*)d_in[10];
  const float* ln_ov_b = (const float*)d_in[11];

  // Workspace layout (248 MiB; aliases annotated with lifetimes):
  //   [0,8M)      WvT (dead after gemm_xw)      -> adjT @0 (4.5M), adjs @5M
  //   [8M,16M)    WoT (dead after gemm_bbf)     -> agg @8M (4M)
  //   [16M,88M)   oeT (written by k_lnT)
  //   [88M,160M)  T (bf16 tanh; read by k_lnT)
  //   [160M,165M) part
  //   [165M,166M) stats
  //   [166M,170M) Yv
  //   [170M,174M) ve_f
  //   [174M,176M) ve_b
  //   [176M,248M) oe_b
  char* ws = (char*)d_ws;
  constexpr size_t OFF_WVT  = 0;
  constexpr size_t OFF_ADJ  = 0;                  // alias (WvT dead)
  constexpr size_t OFF_ADJS = 5ull << 20;         // alias (WvT dead)
  constexpr size_t OFF_WOT  = 8ull << 20;
  constexpr size_t OFF_AGG  = 8ull << 20;         // alias (WoT dead)
  constexpr size_t OFF_OET  = 16ull << 20;
  constexpr size_t OFF_T    = 88ull << 20;
  constexpr size_t OFF_PART = 160ull << 20;
  constexpr size_t OFF_STAT = 165ull << 20;
  constexpr size_t OFF_YV   = 166ull << 20;
  constexpr size_t OFF_VEF  = 170ull << 20;
  constexpr size_t OFF_VEB  = 174ull << 20;
  constexpr size_t OFF_OEB  = 176ull << 20;
  constexpr size_t WS_NEED  = 248ull << 20;
  if (ws_size < WS_NEED) return;

  unsigned short* WvT  = (unsigned short*)(ws + OFF_WVT);
  unsigned short* WoT  = (unsigned short*)(ws + OFF_WOT);
  unsigned short* oeT  = (unsigned short*)(ws + OFF_OET);
  unsigned short* T    = (unsigned short*)(ws + OFF_T);
  float* part          = (float*)(ws + OFF_PART);
  float2* stats        = (float2*)(ws + OFF_STAT);
  float* Yv            = (float*)(ws + OFF_YV);
  float* ve_f          = (float*)(ws + OFF_VEF);
  unsigned short* ve_b = (unsigned short*)(ws + OFF_VEB);
  unsigned short* oe_b = (unsigned short*)(ws + OFF_OEB);
  float* adjT          = (float*)(ws + OFF_ADJ);
  unsigned short* adjs = (unsigned short*)(ws + OFF_ADJS);
  float* agg           = (float*)(ws + OFF_AGG);

  dim3 b256(256);
  // 1) weight transpose+convert (both)
  k_wprep2<<<dim3(32, 32, 2), b256, 0, stream>>>(W_v, W_o, WvT, WoT);
  // 2) branch GEMMs (obj GEMM reads fp32 obj directly; fused tanh+LN partials)
  k_gemm_xw<<<dim3(16, MV / 128), b256, 0, stream>>>(visual, WvT, b_v, Yv);
  k_gemm_bbf<<<dim3(16, MO / 256), dim3(512), 0, stream>>>(obj, WoT, b_o, T, part);
  // 3) LN finish: visual row-wise; obj stats + fused LN/transpose
  k_ep_ln<<<dim3(MV), b256, 0, stream>>>(Yv, nullptr, ln_v_g, ln_v_b, ve_b, ve_f);
  k_stats<<<dim3(MO / 8), b256, 0, stream>>>(part, stats);
  k_lnT<<<dim3(36, 32, 8), b256, 0, stream>>>(T, stats, ln_o_g, ln_o_b, oe_b, oeT);
  // 4) adjacency + softmax
  k_gemm_adj<<<dim3(NOBJ / 64, BS), b256, 0, stream>>>(oe_b, ve_b, adjT);
  k_smax<<<dim3(MV), b256, 0, stream>>>(adjT, adjs);
  // 5) aggregation
  k_gemm_agg<<<dim3(DD / 64, BS), b256, 0, stream>>>(adjs, oeT, agg);
  // 6) final add + tanh + LN -> d_out (fp32)
  k_ep_ln<<<dim3(MV), b256, 0, stream>>>(agg, ve_f, ln_ov_g, ln_ov_b, nullptr, (float*)d_out);
}

// Round 11
// 457.101 us; speedup vs baseline: 1.2294x; 1.2294x over previous
//
#include <hip/hip_runtime.h>
#include <cstdint>
#include <cstddef>

// ---------------------------------------------------------------------------
// EnhancedObj: visual/object attention block, bf16-MFMA implementation.
// Shapes (hardcoded): bs=8, F=64, obj=36, d=2048.
//   MO = 18432 object rows, MV = 512 visual rows, NOBJ = 2304.
// Round 11: revert to the round-9 configuration (best measured, 451.9 us):
//   - obj GEMM: round-3 pipeline (BM=256 BN=128 BK=64, 3 rotating 48KB LDS
//     buffers, counted vmcnt(6), raw s_barrier, XOR-swizzled LDS, XCD
//     swizzle) + fused tanh -> bf16 T + per-row LN partial sums.
//   - k_cvt_bf16 pre-converts obj fp32 -> bf16 (round-10's in-GEMM convert
//     regressed 165 us: extra serial stage on the K-loop critical path).
//   - k_stats + k_lnT: LN finish fused with the oe transpose (one pass).
//   - adj/agg GEMMs at 288/256 blocks.
// ---------------------------------------------------------------------------

typedef __attribute__((ext_vector_type(4))) float f32x4;
typedef __attribute__((ext_vector_type(4))) unsigned int u32x4;
typedef __attribute__((ext_vector_type(8))) short bf16x8;

#define DD 2048
#define BS 8
#define FF 64
#define NOBJ 2304
#define MO 18432
#define MV 512

__device__ __forceinline__ unsigned short f2bf(float f) {
  unsigned int u = __float_as_uint(f);
  u += 0x7fffu + ((u >> 16) & 1u);          // RTNE (inputs finite)
  return (unsigned short)(u >> 16);
}
__device__ __forceinline__ unsigned int pk2(float a, float b) {
  return (unsigned int)f2bf(a) | ((unsigned int)f2bf(b) << 16);
}
__device__ __forceinline__ float bf2f(unsigned short u) {
  return __uint_as_float((unsigned int)u << 16);
}

typedef __attribute__((address_space(1))) const unsigned int gas_u32;
typedef __attribute__((address_space(3))) unsigned int las_u32;
__device__ __forceinline__ void gl_lds16(const void* g, void* l) {
  __builtin_amdgcn_global_load_lds((gas_u32*)g, (las_u32*)l, 16, 0, 0);
}

// --------------------------------------------------------------------------
// fp32 -> bf16 bulk convert. Each thread: 16 elements per iter.
// --------------------------------------------------------------------------
__global__ __launch_bounds__(256) void k_cvt_bf16(const float* __restrict__ X,
                                                  unsigned short* __restrict__ O,
                                                  int n16) {
  int idx = blockIdx.x * 256 + threadIdx.x;
  const int stride = gridDim.x * 256;
  for (int i = idx; i < n16; i += stride) {
    const f32x4* src = (const f32x4*)(X + (size_t)i * 16);
    f32x4 a = src[0], b = src[1], c = src[2], d = src[3];
    u32x4 p = {pk2(a.x, a.y), pk2(a.z, a.w), pk2(b.x, b.y), pk2(b.z, b.w)};
    u32x4 q = {pk2(c.x, c.y), pk2(c.z, c.w), pk2(d.x, d.y), pk2(d.z, d.w)};
    u32x4* dst = (u32x4*)(O + (size_t)i * 16);
    dst[0] = p;
    dst[1] = q;
  }
}

// --------------------------------------------------------------------------
// Both W[k][n] fp32 (2048x2048) -> Wt[n][k] bf16. 64x64 tiles via LDS.
// grid (32, 32, 2): z selects (W_v -> WvT) or (W_o -> WoT).
// --------------------------------------------------------------------------
__global__ __launch_bounds__(256) void k_wprep2(const float* __restrict__ Wv,
                                                const float* __restrict__ Wo,
                                                unsigned short* __restrict__ WvT,
                                                unsigned short* __restrict__ WoT) {
  __shared__ unsigned short sh[64][65];
  const float* W = blockIdx.z ? Wo : Wv;
  unsigned short* Wt = blockIdx.z ? WoT : WvT;
  const int t = threadIdx.x;
  const int kb = blockIdx.x * 64, nb = blockIdx.y * 64;
  {
    const int rk = t >> 2, seg = t & 3;
    const float* src = W + (size_t)(kb + rk) * DD + nb + seg * 16;
#pragma unroll
    for (int q = 0; q < 4; ++q) {
      f32x4 x = *(const f32x4*)(src + q * 4);
      sh[rk][seg * 16 + q * 4 + 0] = f2bf(x.x);
      sh[rk][seg * 16 + q * 4 + 1] = f2bf(x.y);
      sh[rk][seg * 16 + q * 4 + 2] = f2bf(x.z);
      sh[rk][seg * 16 + q * 4 + 3] = f2bf(x.w);
    }
  }
  __syncthreads();
  {
    const int nn = t >> 2, ks = t & 3;
    unsigned int o[8];
#pragma unroll
    for (int j = 0; j < 8; ++j)
      o[j] = (unsigned int)sh[ks * 16 + 2 * j][nn] |
             ((unsigned int)sh[ks * 16 + 2 * j + 1][nn] << 16);
    u32x4 p0 = {o[0], o[1], o[2], o[3]};
    u32x4 p1 = {o[4], o[5], o[6], o[7]};
    unsigned short* dst = Wt + (size_t)(nb + nn) * DD + kb + ks * 16;
    ((u32x4*)dst)[0] = p0;
    ((u32x4*)dst)[1] = p1;
  }
}

// --------------------------------------------------------------------------
// Obj GEMM fused (round-3 pipeline + fused epilogue):
// T[MO][2048] = bf16(tanh(A@Bt^T + bias)); part[row][32][2] = {sum, sumsq}
// of tanh over 64-col groups.
// BM=256 BN=128 BK=64, 512 thr = 8 waves (wm 0..3, wn 0..1), 64x64 out/wave.
// 3 LDS buffers rotate; counted vmcnt(6) + raw s_barrier per K-step.
// LDS: row-major, row r's 16B chunk at phys slot s holds logical
// k16 = s ^ (r&7). grid = (16, 72); XCD-bijective swizzle (1152 wgs).
// --------------------------------------------------------------------------
__global__ __launch_bounds__(512, 1) void k_gemm_bbf(const unsigned short* __restrict__ A,
                                                     const unsigned short* __restrict__ Bt,
                                                     const float* __restrict__ bias,
                                                     unsigned short* __restrict__ T,
                                                     float* __restrict__ part) {
  // per buffer: A tile 256x64 (16384 e) + B tile 128x64 (8192 e) = 48 KiB
  __shared__ __align__(16) unsigned short lds[3 * 24576];
  const int tid = threadIdx.x;
  const int lane = tid & 63, wave = tid >> 6;
  const int r = lane & 15, g = lane >> 4;
  const int wm = wave >> 1, wn = wave & 1;

  // XCD-aware bijective remap (nwg = 1152, %8 == 0, per = 144)
  const int orig = blockIdx.y * 16 + blockIdx.x;
  const int lin = (orig & 7) * 144 + (orig >> 3);
  const int bm = (lin >> 4) * 256;
  const int bn = (lin & 15) * 128;

  // staging: thread covers 16B chunk c = q*512+tid -> row = c>>3, slot = c&7
  // physical slot holds logical k16 = slot ^ (row&7)  (XOR involution)
  const int srow = tid >> 3;                    // 0..63 (row within q-block)
  const int k16s = (tid & 7) ^ (srow & 7);
  const unsigned short* aSrc[4];
#pragma unroll
  for (int q = 0; q < 4; ++q)
    aSrc[q] = A + (size_t)(bm + q * 64 + srow) * DD + k16s * 8;
  const unsigned short* bSrc[2];
#pragma unroll
  for (int q = 0; q < 2; ++q)
    bSrc[q] = Bt + (size_t)(bn + q * 64 + srow) * DD + k16s * 8;

  auto stage = [&](int buf, int kt) {
    unsigned short* ab = lds + buf * 24576;
    unsigned short* bb = ab + 16384;
    const size_t ko = (size_t)kt * 64;
#pragma unroll
    for (int q = 0; q < 4; ++q)
      gl_lds16(aSrc[q] + ko, ab + ((q * 512 + tid) << 3));
#pragma unroll
    for (int q = 0; q < 2; ++q)
      gl_lds16(bSrc[q] + ko, bb + ((q * 512 + tid) << 3));
  };

  // frag-read swizzled slot offsets (elements): slot = (kk*4+g) ^ (r&7)
  const int rs = r & 7;
  const int sa0 = ((0 + g) ^ rs) * 8;
  const int sa1 = ((4 + g) ^ rs) * 8;
  const int arow0 = wm * 64 + r;
  const int brow0 = wn * 64 + r;

  f32x4 acc[4][4] = {};
  stage(0, 0);
  stage(1, 1);
  asm volatile("s_waitcnt vmcnt(6)" ::: "memory");  // tile0 landed (per wave)
  __builtin_amdgcn_s_barrier();

  for (int kt = 0; kt < DD / 64; ++kt) {
    const int cur = kt % 3;
    if (kt + 2 < DD / 64) stage((kt + 2) % 3, kt + 2);
    const unsigned short* ab = lds + cur * 24576;
    const unsigned short* bb = ab + 16384;
    bf16x8 af[4][2], bfr[4][2];
#pragma unroll
    for (int mi = 0; mi < 4; ++mi) {
      const int ro = (arow0 + mi * 16) * 64;
      af[mi][0] = *(const bf16x8*)(ab + ro + sa0);
      af[mi][1] = *(const bf16x8*)(ab + ro + sa1);
    }
#pragma unroll
    for (int ni = 0; ni < 4; ++ni) {
      const int ro = (brow0 + ni * 16) * 64;
      bfr[ni][0] = *(const bf16x8*)(bb + ro + sa0);
      bfr[ni][1] = *(const bf16x8*)(bb + ro + sa1);
    }
    __builtin_amdgcn_s_setprio(1);
#pragma unroll
    for (int mi = 0; mi < 4; ++mi)
#pragma unroll
      for (int ni = 0; ni < 4; ++ni) {
        acc[mi][ni] = __builtin_amdgcn_mfma_f32_16x16x32_bf16(af[mi][0], bfr[ni][0], acc[mi][ni], 0, 0, 0);
        acc[mi][ni] = __builtin_amdgcn_mfma_f32_16x16x32_bf16(af[mi][1], bfr[ni][1], acc[mi][ni], 0, 0, 0);
      }
    __builtin_amdgcn_s_setprio(0);
    if (kt < DD / 64 - 2) {
      asm volatile("s_waitcnt vmcnt(6)" ::: "memory");  // tile kt+1 landed
    } else {
      asm volatile("s_waitcnt vmcnt(0)" ::: "memory");  // tail drain
    }
    __builtin_amdgcn_s_barrier();
  }

  // ---- fused epilogue: bias + tanh -> bf16 T, per-row partial LN sums ----
  float bv[4];
#pragma unroll
  for (int ni = 0; ni < 4; ++ni) bv[ni] = bias[bn + wn * 64 + ni * 16 + r];
  const int slot = ((lin & 15) << 1) + wn;  // 32 col-groups of 64
#pragma unroll
  for (int mi = 0; mi < 4; ++mi) {
#pragma unroll
    for (int i2 = 0; i2 < 4; ++i2) {
      const int row = bm + wm * 64 + mi * 16 + g * 4 + i2;
      unsigned short* trow = T + (size_t)row * DD + bn + wn * 64 + r;
      float s1 = 0.f, s2 = 0.f;
#pragma unroll
      for (int ni = 0; ni < 4; ++ni) {
        const float tv = tanhf(acc[mi][ni][i2] + bv[ni]);
        trow[ni * 16] = f2bf(tv);
        s1 += tv;
        s2 += tv * tv;
      }
#pragma unroll
      for (int m = 1; m < 16; m <<= 1) {
        s1 += __shfl_xor(s1, m, 64);
        s2 += __shfl_xor(s2, m, 64);
      }
      if (r == 0) {
        float2 p2 = make_float2(s1, s2);
        *(float2*)(part + (size_t)row * 64 + slot * 2) = p2;
      }
    }
  }
}

// --------------------------------------------------------------------------
// part[row][32][2] -> stats[row] = (mean, rstd). One 32-lane group per row.
// grid = MO/8, block 256.
// --------------------------------------------------------------------------
__global__ __launch_bounds__(256) void k_stats(const float* __restrict__ part,
                                               float2* __restrict__ stats) {
  const int t = threadIdx.x;
  const int row = blockIdx.x * 8 + (t >> 5);
  const int i = t & 31;
  float2 p = ((const float2*)(part + (size_t)row * 64))[i];
  float s1 = p.x, s2 = p.y;
#pragma unroll
  for (int m = 1; m < 32; m <<= 1) {
    s1 += __shfl_xor(s1, m, 64);
    s2 += __shfl_xor(s2, m, 64);
  }
  if (i == 0) {
    const float mean = s1 * (1.0f / DD);
    const float var = s2 * (1.0f / DD) - mean * mean;
    stats[row] = make_float2(mean, rsqrtf(var + 1e-5f));
  }
}

// --------------------------------------------------------------------------
// Fused LN + dual-layout write: o = (T - mean)*rstd*g + b (bf16);
// writes oe[b][n][d] (row-major) AND oeT[b][d][n] (LDS transpose).
// grid (36, 32, 8), block 256.
// --------------------------------------------------------------------------
__global__ __launch_bounds__(256) void k_lnT(const unsigned short* __restrict__ T,
                                             const float2* __restrict__ stats,
                                             const float* __restrict__ gw,
                                             const float* __restrict__ bw,
                                             unsigned short* __restrict__ oe,
                                             unsigned short* __restrict__ oeT) {
  __shared__ unsigned short sh[64][65];
  const int t = threadIdx.x;
  const int b = blockIdx.z, nt = blockIdx.x, dt = blockIdx.y;
  {
    const int nn = t >> 2, seg = t & 3;
    const int row = b * NOBJ + nt * 64 + nn;
    const size_t base = (size_t)row * DD + dt * 64 + seg * 16;
    u32x4 x0 = ((const u32x4*)(T + base))[0];
    u32x4 x1 = ((const u32x4*)(T + base))[1];
    const float2 st = stats[row];
    const float* gp = gw + dt * 64 + seg * 16;
    const float* bp = bw + dt * 64 + seg * 16;
    f32x4 gq[4], bq[4];
#pragma unroll
    for (int q = 0; q < 4; ++q) {
      gq[q] = ((const f32x4*)gp)[q];
      bq[q] = ((const f32x4*)bp)[q];
    }
    const unsigned short* px0 = (const unsigned short*)&x0;
    const unsigned short* px1 = (const unsigned short*)&x1;
    unsigned short ov[16];
#pragma unroll
    for (int j = 0; j < 8; ++j) {
      const float v = bf2f(px0[j]);
      ov[j] = f2bf((v - st.x) * st.y * gq[j >> 2][j & 3] + bq[j >> 2][j & 3]);
    }
#pragma unroll
    for (int j = 0; j < 8; ++j) {
      const float v = bf2f(px1[j]);
      ov[8 + j] = f2bf((v - st.x) * st.y * gq[2 + (j >> 2)][j & 3] + bq[2 + (j >> 2)][j & 3]);
    }
    u32x4 o0 = {(unsigned int)ov[0] | ((unsigned int)ov[1] << 16),
                (unsigned int)ov[2] | ((unsigned int)ov[3] << 16),
                (unsigned int)ov[4] | ((unsigned int)ov[5] << 16),
                (unsigned int)ov[6] | ((unsigned int)ov[7] << 16)};
    u32x4 o1 = {(unsigned int)ov[8] | ((unsigned int)ov[9] << 16),
                (unsigned int)ov[10] | ((unsigned int)ov[11] << 16),
                (unsigned int)ov[12] | ((unsigned int)ov[13] << 16),
                (unsigned int)ov[14] | ((unsigned int)ov[15] << 16)};
    ((u32x4*)(oe + base))[0] = o0;
    ((u32x4*)(oe + base))[1] = o1;
#pragma unroll
    for (int j = 0; j < 16; ++j) sh[nn][seg * 16 + j] = ov[j];
  }
  __syncthreads();
  {
    const int dd = t >> 2, ns = t & 3;
    unsigned int o[8];
#pragma unroll
    for (int j = 0; j < 8; ++j)
      o[j] = (unsigned int)sh[ns * 16 + 2 * j][dd] |
             ((unsigned int)sh[ns * 16 + 2 * j + 1][dd] << 16);
    u32x4 p0 = {o[0], o[1], o[2], o[3]};
    u32x4 p1 = {o[4], o[5], o[6], o[7]};
    unsigned short* dst = oeT + ((size_t)b * DD + dt * 64 + dd) * NOBJ + nt * 64 + ns * 16;
    ((u32x4*)dst)[0] = p0;
    ((u32x4*)dst)[1] = p1;
  }
}

// --------------------------------------------------------------------------
// Y[M][2048] = X[M][2048](fp32) @ W + bias (inline convert). Visual branch.
// --------------------------------------------------------------------------
__global__ __launch_bounds__(256) void k_gemm_xw(const float* __restrict__ X,
                                                 const unsigned short* __restrict__ Wt,
                                                 const float* __restrict__ bias,
                                                 float* __restrict__ Y) {
  __shared__ __align__(16) unsigned short As[128 * 32];
  __shared__ __align__(16) unsigned short Bs[128 * 32];
  const int t = threadIdx.x;
  const int lane = t & 63, wave = t >> 6;
  const int r = lane & 15, g = lane >> 4;
  const int wm = wave >> 1, wn = wave & 1;
  const int bm = blockIdx.y * 128, bn = blockIdx.x * 128;
  const int arow = t >> 1, ah = t & 1;
  f32x4 acc[4][4] = {};
  const float* aptr = X + (size_t)(bm + arow) * DD + ah * 16;
  const unsigned short* bptr = Wt + (size_t)(bn + arow) * DD + ah * 16;
  for (int kt = 0; kt < DD / 32; ++kt) {
    const int kb = kt * 32;
    f32x4 a0 = *(const f32x4*)(aptr + kb);
    f32x4 a1 = *(const f32x4*)(aptr + kb + 4);
    f32x4 a2 = *(const f32x4*)(aptr + kb + 8);
    f32x4 a3 = *(const f32x4*)(aptr + kb + 12);
    u32x4 b0 = *(const u32x4*)(bptr + kb);
    u32x4 b1 = *(const u32x4*)(bptr + kb + 8);
    __syncthreads();
    u32x4 p0 = {pk2(a0.x, a0.y), pk2(a0.z, a0.w), pk2(a1.x, a1.y), pk2(a1.z, a1.w)};
    u32x4 p1 = {pk2(a2.x, a2.y), pk2(a2.z, a2.w), pk2(a3.x, a3.y), pk2(a3.z, a3.w)};
    ((u32x4*)As)[arow * 4 + ah * 2 + 0] = p0;
    ((u32x4*)As)[arow * 4 + ah * 2 + 1] = p1;
    ((u32x4*)Bs)[arow * 4 + ah * 2 + 0] = b0;
    ((u32x4*)Bs)[arow * 4 + ah * 2 + 1] = b1;
    __syncthreads();
    bf16x8 af[4], bfr[4];
#pragma unroll
    for (int m = 0; m < 4; ++m) af[m] = ((const bf16x8*)As)[(wm * 64 + m * 16 + r) * 4 + g];
#pragma unroll
    for (int n = 0; n < 4; ++n) bfr[n] = ((const bf16x8*)Bs)[(wn * 64 + n * 16 + r) * 4 + g];
#pragma unroll
    for (int m = 0; m < 4; ++m)
#pragma unroll
      for (int n = 0; n < 4; ++n)
        acc[m][n] = __builtin_amdgcn_mfma_f32_16x16x32_bf16(af[m], bfr[n], acc[m][n], 0, 0, 0);
  }
#pragma unroll
  for (int m = 0; m < 4; ++m) {
    const int row0 = bm + wm * 64 + m * 16 + g * 4;
#pragma unroll
    for (int n = 0; n < 4; ++n) {
      const int col = bn + wn * 64 + n * 16 + r;
      const float bvx = bias[col];
#pragma unroll
      for (int i = 0; i < 4; ++i)
        Y[(size_t)(row0 + i) * DD + col] = acc[m][n][i] + bvx;
    }
  }
}

// --------------------------------------------------------------------------
// Row-wise: t = tanh(Y[row] (+ Y2[row])); LN(t)*g+b -> optional bf16 / fp32.
// --------------------------------------------------------------------------
__global__ __launch_bounds__(256) void k_ep_ln(const float* __restrict__ Y,
                                               const float* __restrict__ Y2,
                                               const float* __restrict__ gw,
                                               const float* __restrict__ bw,
                                               unsigned short* __restrict__ obf,
                                               float* __restrict__ of32) {
  const int row = blockIdx.x, t = threadIdx.x;
  const size_t base = (size_t)row * DD + t * 8;
  f32x4 v0 = ((const f32x4*)(Y + base))[0];
  f32x4 v1 = ((const f32x4*)(Y + base))[1];
  if (Y2 != nullptr) {
    v0 += ((const f32x4*)(Y2 + base))[0];
    v1 += ((const f32x4*)(Y2 + base))[1];
  }
  float tv[8];
#pragma unroll
  for (int j = 0; j < 4; ++j) {
    tv[j] = tanhf(v0[j]);
    tv[4 + j] = tanhf(v1[j]);
  }
  float s1 = 0.f, s2 = 0.f;
#pragma unroll
  for (int j = 0; j < 8; ++j) {
    s1 += tv[j];
    s2 += tv[j] * tv[j];
  }
#pragma unroll
  for (int m = 1; m < 64; m <<= 1) {
    s1 += __shfl_xor(s1, m, 64);
    s2 += __shfl_xor(s2, m, 64);
  }
  __shared__ float r1[4], r2[4];
  const int wave = t >> 6;
  if ((t & 63) == 0) {
    r1[wave] = s1;
    r2[wave] = s2;
  }
  __syncthreads();
  const float S1 = r1[0] + r1[1] + r1[2] + r1[3];
  const float S2 = r2[0] + r2[1] + r2[2] + r2[3];
  const float mean = S1 * (1.0f / DD);
  const float var = S2 * (1.0f / DD) - mean * mean;
  const float rstd = rsqrtf(var + 1e-5f);
  f32x4 g0 = ((const f32x4*)(gw + t * 8))[0], g1 = ((const f32x4*)(gw + t * 8))[1];
  f32x4 bb0 = ((const f32x4*)(bw + t * 8))[0], bb1 = ((const f32x4*)(bw + t * 8))[1];
  float o[8];
#pragma unroll
  for (int j = 0; j < 4; ++j) {
    o[j] = (tv[j] - mean) * rstd * g0[j] + bb0[j];
    o[4 + j] = (tv[4 + j] - mean) * rstd * g1[j] + bb1[j];
  }
  if (obf != nullptr) {
    u32x4 p = {pk2(o[0], o[1]), pk2(o[2], o[3]), pk2(o[4], o[5]), pk2(o[6], o[7])};
    *((u32x4*)(obf + base)) = p;
  }
  if (of32 != nullptr) {
    f32x4 w0 = {o[0], o[1], o[2], o[3]}, w1 = {o[4], o[5], o[6], o[7]};
    ((f32x4*)(of32 + base))[0] = w0;
    ((f32x4*)(of32 + base))[1] = w1;
  }
}

// --------------------------------------------------------------------------
// adjT[b][f][n] = (oe[b][n][:] . ve[b][f][:]) / sqrt(2048).
// BM=64(n), 256 thr 4 waves. grid (36, 8) = 288 blocks.
// --------------------------------------------------------------------------
__global__ __launch_bounds__(256) void k_gemm_adj(const unsigned short* __restrict__ oe,
                                                  const unsigned short* __restrict__ veb,
                                                  float* __restrict__ adjT) {
  __shared__ __align__(16) unsigned short As[64 * 32];
  __shared__ __align__(16) unsigned short Bs[64 * 32];
  const int t = threadIdx.x;
  const int lane = t & 63, wave = t >> 6;
  const int r = lane & 15, g = lane >> 4;
  const int wm = wave >> 1, wn = wave & 1;
  const int b = blockIdx.y, bm = blockIdx.x * 64;
  const int arow = t >> 2, aseg = t & 3;
  f32x4 acc[2][2] = {};
  const unsigned short* aptr = oe + ((size_t)b * NOBJ + bm + arow) * DD + aseg * 8;
  const unsigned short* bptr = veb + ((size_t)b * FF + arow) * DD + aseg * 8;
  for (int kt = 0; kt < DD / 32; ++kt) {
    const int kb = kt * 32;
    u32x4 a0 = *(const u32x4*)(aptr + kb);
    u32x4 bvx = *(const u32x4*)(bptr + kb);
    __syncthreads();
    ((u32x4*)As)[arow * 4 + aseg] = a0;
    ((u32x4*)Bs)[arow * 4 + aseg] = bvx;
    __syncthreads();
    bf16x8 af[2], bfr[2];
#pragma unroll
    for (int m = 0; m < 2; ++m) af[m] = ((const bf16x8*)As)[(wm * 32 + m * 16 + r) * 4 + g];
#pragma unroll
    for (int n = 0; n < 2; ++n) bfr[n] = ((const bf16x8*)Bs)[(wn * 32 + n * 16 + r) * 4 + g];
#pragma unroll
    for (int m = 0; m < 2; ++m)
#pragma unroll
      for (int n = 0; n < 2; ++n)
        acc[m][n] = __builtin_amdgcn_mfma_f32_16x16x32_bf16(af[m], bfr[n], acc[m][n], 0, 0, 0);
  }
  const float scale = 0.02209708691207961f;  // 1/sqrt(2048)
#pragma unroll
  for (int m = 0; m < 2; ++m)
#pragma unroll
    for (int n = 0; n < 2; ++n) {
      const int f = wn * 32 + n * 16 + r;
      const int n0 = bm + wm * 32 + m * 16 + g * 4;
      f32x4 v = acc[m][n];
      v *= scale;
      *(f32x4*)(adjT + ((size_t)b * FF + f) * NOBJ + n0) = v;
    }
}

// --------------------------------------------------------------------------
// Row softmax over 2304 (rows of adjT), write bf16. grid = 512 rows.
// --------------------------------------------------------------------------
__global__ __launch_bounds__(256) void k_smax(const float* __restrict__ adjT,
                                              unsigned short* __restrict__ out) {
  const int t = threadIdx.x;
  const size_t base = (size_t)blockIdx.x * NOBJ;
  float v[9];
#pragma unroll
  for (int j = 0; j < 9; ++j) v[j] = adjT[base + t + j * 256];
  float m = v[0];
#pragma unroll
  for (int j = 1; j < 9; ++j) m = fmaxf(m, v[j]);
#pragma unroll
  for (int s = 1; s < 64; s <<= 1) m = fmaxf(m, __shfl_xor(m, s, 64));
  __shared__ float rm[4], rs[4];
  const int wave = t >> 6;
  if ((t & 63) == 0) rm[wave] = m;
  __syncthreads();
  m = fmaxf(fmaxf(rm[0], rm[1]), fmaxf(rm[2], rm[3]));
  float e[9];
  float s = 0.f;
#pragma unroll
  for (int j = 0; j < 9; ++j) {
    e[j] = __expf(v[j] - m);
    s += e[j];
  }
#pragma unroll
  for (int q = 1; q < 64; q <<= 1) s += __shfl_xor(s, q, 64);
  if ((t & 63) == 0) rs[wave] = s;
  __syncthreads();
  const float S = rs[0] + rs[1] + rs[2] + rs[3];
  const float inv = 1.0f / S;
#pragma unroll
  for (int j = 0; j < 9; ++j) out[base + t + j * 256] = f2bf(e[j] * inv);
}

// --------------------------------------------------------------------------
// agg[b][f][d] = sum_n adj_sm[b][f][n] * oeT[b][d][n].
// BN=64(d), 256 thr 4 waves. grid (32, 8) = 256 blocks.
// --------------------------------------------------------------------------
__global__ __launch_bounds__(256) void k_gemm_agg(const unsigned short* __restrict__ adjsm,
                                                  const unsigned short* __restrict__ oeT,
                                                  float* __restrict__ agg) {
  __shared__ __align__(16) unsigned short As[64 * 32];
  __shared__ __align__(16) unsigned short Bs[64 * 32];
  const int t = threadIdx.x;
  const int lane = t & 63, wave = t >> 6;
  const int r = lane & 15, g = lane >> 4;
  const int wm = wave >> 1, wn = wave & 1;
  const int b = blockIdx.y, bn = blockIdx.x * 64;
  const int arow = t >> 2, aseg = t & 3;
  f32x4 acc[2][2] = {};
  const unsigned short* aptr = adjsm + ((size_t)b * FF + arow) * NOBJ + aseg * 8;
  const unsigned short* bptr = oeT + ((size_t)b * DD + bn + arow) * NOBJ + aseg * 8;
  for (int kt = 0; kt < NOBJ / 32; ++kt) {
    const int kb = kt * 32;
    u32x4 av = *(const u32x4*)(aptr + kb);
    u32x4 bvx = *(const u32x4*)(bptr + kb);
    __syncthreads();
    ((u32x4*)As)[arow * 4 + aseg] = av;
    ((u32x4*)Bs)[arow * 4 + aseg] = bvx;
    __syncthreads();
    bf16x8 af[2], bfr[2];
#pragma unroll
    for (int m = 0; m < 2; ++m) af[m] = ((const bf16x8*)As)[(wm * 32 + m * 16 + r) * 4 + g];
#pragma unroll
    for (int n = 0; n < 2; ++n) bfr[n] = ((const bf16x8*)Bs)[(wn * 32 + n * 16 + r) * 4 + g];
#pragma unroll
    for (int m = 0; m < 2; ++m)
#pragma unroll
      for (int n = 0; n < 2; ++n)
        acc[m][n] = __builtin_amdgcn_mfma_f32_16x16x32_bf16(af[m], bfr[n], acc[m][n], 0, 0, 0);
  }
#pragma unroll
  for (int m = 0; m < 2; ++m)
#pragma unroll
    for (int n = 0; n < 2; ++n) {
      const int d = bn + wn * 32 + n * 16 + r;
#pragma unroll
      for (int i = 0; i < 4; ++i) {
        const int f = wm * 32 + m * 16 + g * 4 + i;
        agg[((size_t)b * FF + f) * DD + d] = acc[m][n][i];
      }
    }
}

// --------------------------------------------------------------------------

extern "C" void kernel_launch(void* const* d_in, const int* in_sizes, int n_in,
                              void* d_out, int out_size, void* d_ws, size_t ws_size,
                              hipStream_t stream) {
  (void)in_sizes; (void)n_in; (void)out_size;
  const float* visual = (const float*)d_in[0];
  const float* obj    = (const float*)d_in[1];
  const float* W_v    = (const float*)d_in[2];
  const float* b_v    = (const float*)d_in[3];
  const float* W_o    = (const float*)d_in[4];
  const float* b_o    = (const float*)d_in[5];
  const float* ln_v_g = (const float*)d_in[6];
  const float* ln_v_b = (const float*)d_in[7];
  const float* ln_o_g = (const float*)d_in[8];
  const float* ln_o_b = (const float*)d_in[9];
  const float* ln_ov_g = (const float*)d_in[10];
  const float* ln_ov_b = (const float*)d_in[11];

  // Workspace layout (248 MiB; aliases annotated with lifetimes):
  //   [0,8M)      WvT (dead after gemm_xw)      -> adjT @0 (4.5M), adjs @5M
  //   [8M,16M)    WoT (dead after gemm_bbf)     -> agg @8M (4M)
  //   [16M,88M)   objb (dead after gemm_bbf)    -> oeT (written by k_lnT)
  //   [88M,160M)  T (bf16 tanh; read by k_lnT)
  //   [160M,165M) part
  //   [165M,166M) stats
  //   [166M,170M) Yv
  //   [170M,174M) ve_f
  //   [174M,176M) ve_b
  //   [176M,248M) oe_b
  char* ws = (char*)d_ws;
  constexpr size_t OFF_WVT  = 0;
  constexpr size_t OFF_ADJ  = 0;                  // alias (WvT dead)
  constexpr size_t OFF_ADJS = 5ull << 20;         // alias (WvT dead)
  constexpr size_t OFF_WOT  = 8ull << 20;
  constexpr size_t OFF_AGG  = 8ull << 20;         // alias (WoT dead)
  constexpr size_t OFF_OBJB = 16ull << 20;
  constexpr size_t OFF_OET  = 16ull << 20;        // alias (objb dead)
  constexpr size_t OFF_T    = 88ull << 20;
  constexpr size_t OFF_PART = 160ull << 20;
  constexpr size_t OFF_STAT = 165ull << 20;
  constexpr size_t OFF_YV   = 166ull << 20;
  constexpr size_t OFF_VEF  = 170ull << 20;
  constexpr size_t OFF_VEB  = 174ull << 20;
  constexpr size_t OFF_OEB  = 176ull << 20;
  constexpr size_t WS_NEED  = 248ull << 20;
  if (ws_size < WS_NEED) return;

  unsigned short* WvT  = (unsigned short*)(ws + OFF_WVT);
  unsigned short* WoT  = (unsigned short*)(ws + OFF_WOT);
  unsigned short* objb = (unsigned short*)(ws + OFF_OBJB);
  unsigned short* oeT  = (unsigned short*)(ws + OFF_OET);
  unsigned short* T    = (unsigned short*)(ws + OFF_T);
  float* part          = (float*)(ws + OFF_PART);
  float2* stats        = (float2*)(ws + OFF_STAT);
  float* Yv            = (float*)(ws + OFF_YV);
  float* ve_f          = (float*)(ws + OFF_VEF);
  unsigned short* ve_b = (unsigned short*)(ws + OFF_VEB);
  unsigned short* oe_b = (unsigned short*)(ws + OFF_OEB);
  float* adjT          = (float*)(ws + OFF_ADJ);
  unsigned short* adjs = (unsigned short*)(ws + OFF_ADJS);
  float* agg           = (float*)(ws + OFF_AGG);

  dim3 b256(256);
  // 1) weight transpose+convert (both), obj fp32->bf16
  k_wprep2<<<dim3(32, 32, 2), b256, 0, stream>>>(W_v, W_o, WvT, WoT);
  k_cvt_bf16<<<dim3(2048), b256, 0, stream>>>(obj, objb, MO * DD / 16);
  // 2) branch GEMMs (obj GEMM fused with tanh + LN partials)
  k_gemm_xw<<<dim3(16, MV / 128), b256, 0, stream>>>(visual, WvT, b_v, Yv);
  k_gemm_bbf<<<dim3(16, MO / 256), dim3(512), 0, stream>>>(objb, WoT, b_o, T, part);
  // 3) LN finish: visual row-wise; obj stats + fused LN/transpose
  k_ep_ln<<<dim3(MV), b256, 0, stream>>>(Yv, nullptr, ln_v_g, ln_v_b, ve_b, ve_f);
  k_stats<<<dim3(MO / 8), b256, 0, stream>>>(part, stats);
  k_lnT<<<dim3(36, 32, 8), b256, 0, stream>>>(T, stats, ln_o_g, ln_o_b, oe_b, oeT);
  // 4) adjacency + softmax
  k_gemm_adj<<<dim3(NOBJ / 64, BS), b256, 0, stream>>>(oe_b, ve_b, adjT);
  k_smax<<<dim3(MV), b256, 0, stream>>>(adjT, adjs);
  // 5) aggregation
  k_gemm_agg<<<dim3(DD / 64, BS), b256, 0, stream>>>(adjs, oeT, agg);
  // 6) final add + tanh + LN -> d_out (fp32)
  k_ep_ln<<<dim3(MV), b256, 0, stream>>>(agg, ve_f, ln_ov_g, ln_ov_b, nullptr, (float*)d_out);
}

// Round 12
// 432.460 us; speedup vs baseline: 1.2995x; 1.0570x over previous
//
#include <hip/hip_runtime.h>
#include <cstdint>
#include <cstddef>

// ---------------------------------------------------------------------------
// EnhancedObj: visual/object attention block, bf16-MFMA implementation.
// Shapes (hardcoded): bs=8, F=64, obj=36, d=2048.
//   MO = 18432 object rows, MV = 512 visual rows, NOBJ = 2304.
// Round 12: obj GEMM = round-3/8 pipeline at BK=32 so the 3-buffer rotation
// fits 72 KB LDS -> 2 blocks/CU (4 waves/SIMD; was 1 block / 2 waves).
// Same rotation, counted vmcnt(3) (3 loads/stage), raw s_barrier, XCD
// swizzle, fused tanh+LN-partial epilogue. BK=32 swizzle derived fresh:
// phys_slot = logical ^ ((row>>1)&3)  (4 slots/row of 64B) -> frag reads
// land 8 lanes per 16B bank-group (b128 optimum); staging source stays
// 64B-contiguous per 4-lane group; slot formula is issue-invariant.
// Per-element accumulation k-order identical -> bit-identical output.
// ---------------------------------------------------------------------------

typedef __attribute__((ext_vector_type(4))) float f32x4;
typedef __attribute__((ext_vector_type(4))) unsigned int u32x4;
typedef __attribute__((ext_vector_type(8))) short bf16x8;

#define DD 2048
#define BS 8
#define FF 64
#define NOBJ 2304
#define MO 18432
#define MV 512

__device__ __forceinline__ unsigned short f2bf(float f) {
  unsigned int u = __float_as_uint(f);
  u += 0x7fffu + ((u >> 16) & 1u);          // RTNE (inputs finite)
  return (unsigned short)(u >> 16);
}
__device__ __forceinline__ unsigned int pk2(float a, float b) {
  return (unsigned int)f2bf(a) | ((unsigned int)f2bf(b) << 16);
}
__device__ __forceinline__ float bf2f(unsigned short u) {
  return __uint_as_float((unsigned int)u << 16);
}

typedef __attribute__((address_space(1))) const unsigned int gas_u32;
typedef __attribute__((address_space(3))) unsigned int las_u32;
__device__ __forceinline__ void gl_lds16(const void* g, void* l) {
  __builtin_amdgcn_global_load_lds((gas_u32*)g, (las_u32*)l, 16, 0, 0);
}

// --------------------------------------------------------------------------
// fp32 -> bf16 bulk convert. Each thread: 16 elements per iter.
// --------------------------------------------------------------------------
__global__ __launch_bounds__(256) void k_cvt_bf16(const float* __restrict__ X,
                                                  unsigned short* __restrict__ O,
                                                  int n16) {
  int idx = blockIdx.x * 256 + threadIdx.x;
  const int stride = gridDim.x * 256;
  for (int i = idx; i < n16; i += stride) {
    const f32x4* src = (const f32x4*)(X + (size_t)i * 16);
    f32x4 a = src[0], b = src[1], c = src[2], d = src[3];
    u32x4 p = {pk2(a.x, a.y), pk2(a.z, a.w), pk2(b.x, b.y), pk2(b.z, b.w)};
    u32x4 q = {pk2(c.x, c.y), pk2(c.z, c.w), pk2(d.x, d.y), pk2(d.z, d.w)};
    u32x4* dst = (u32x4*)(O + (size_t)i * 16);
    dst[0] = p;
    dst[1] = q;
  }
}

// --------------------------------------------------------------------------
// Both W[k][n] fp32 (2048x2048) -> Wt[n][k] bf16. 64x64 tiles via LDS.
// grid (32, 32, 2): z selects (W_v -> WvT) or (W_o -> WoT).
// --------------------------------------------------------------------------
__global__ __launch_bounds__(256) void k_wprep2(const float* __restrict__ Wv,
                                                const float* __restrict__ Wo,
                                                unsigned short* __restrict__ WvT,
                                                unsigned short* __restrict__ WoT) {
  __shared__ unsigned short sh[64][65];
  const float* W = blockIdx.z ? Wo : Wv;
  unsigned short* Wt = blockIdx.z ? WoT : WvT;
  const int t = threadIdx.x;
  const int kb = blockIdx.x * 64, nb = blockIdx.y * 64;
  {
    const int rk = t >> 2, seg = t & 3;
    const float* src = W + (size_t)(kb + rk) * DD + nb + seg * 16;
#pragma unroll
    for (int q = 0; q < 4; ++q) {
      f32x4 x = *(const f32x4*)(src + q * 4);
      sh[rk][seg * 16 + q * 4 + 0] = f2bf(x.x);
      sh[rk][seg * 16 + q * 4 + 1] = f2bf(x.y);
      sh[rk][seg * 16 + q * 4 + 2] = f2bf(x.z);
      sh[rk][seg * 16 + q * 4 + 3] = f2bf(x.w);
    }
  }
  __syncthreads();
  {
    const int nn = t >> 2, ks = t & 3;
    unsigned int o[8];
#pragma unroll
    for (int j = 0; j < 8; ++j)
      o[j] = (unsigned int)sh[ks * 16 + 2 * j][nn] |
             ((unsigned int)sh[ks * 16 + 2 * j + 1][nn] << 16);
    u32x4 p0 = {o[0], o[1], o[2], o[3]};
    u32x4 p1 = {o[4], o[5], o[6], o[7]};
    unsigned short* dst = Wt + (size_t)(nb + nn) * DD + kb + ks * 16;
    ((u32x4*)dst)[0] = p0;
    ((u32x4*)dst)[1] = p1;
  }
}

// --------------------------------------------------------------------------
// Obj GEMM fused: T[MO][2048] = bf16(tanh(A@Bt^T + bias));
// part[row][32][2] = {sum, sumsq} of tanh over 64-col groups.
// BM=256 BN=128 BK=32, 512 thr = 8 waves (wm 0..3, wn 0..1), 64x64 out/wave.
// 3 LDS buffers (24 KB each, 72 KB total -> 2 blocks/CU) rotate; iter kt
// computes buf[kt%3], stages tile kt+2 (3 x gl_lds16) into buf[(kt+2)%3];
// end-of-iter s_waitcnt vmcnt(3) (tile kt+1 landed; kt+2's 3 loads stay in
// flight ACROSS the barrier) + raw s_barrier.
// LDS: row-major, row r (64B = 4 x 16B slots); phys slot s holds logical
// k16 = s ^ ((r>>1)&3). grid = (16, 72); XCD-bijective swizzle (1152 wgs).
// --------------------------------------------------------------------------
__global__ __launch_bounds__(512, 4) void k_gemm_bbf(const unsigned short* __restrict__ A,
                                                     const unsigned short* __restrict__ Bt,
                                                     const float* __restrict__ bias,
                                                     unsigned short* __restrict__ T,
                                                     float* __restrict__ part) {
  // per buffer: A tile 256x32 (8192 e) + B tile 128x32 (4096 e) = 24 KiB
  __shared__ __align__(16) unsigned short lds[3 * 12288];
  const int tid = threadIdx.x;
  const int lane = tid & 63, wave = tid >> 6;
  const int r = lane & 15, g = lane >> 4;
  const int wm = wave >> 1, wn = wave & 1;

  // XCD-aware bijective remap (nwg = 1152, %8 == 0, per = 144)
  const int orig = blockIdx.y * 16 + blockIdx.x;
  const int lin = (orig & 7) * 144 + (orig >> 3);
  const int bm = (lin >> 4) * 256;
  const int bn = (lin & 15) * 128;

  // staging: chunk c = q*512 + tid -> row = c>>2, phys slot = c&3 = tid&3,
  // logical k16 = (tid&3) ^ ((row>>1)&3) = (tid&3) ^ ((tid>>3)&3)
  // (q*128 rows shift row>>1 by multiples of 4 -> &3 unchanged).
  const int k16s = (tid & 3) ^ ((tid >> 3) & 3);
  const int srow = tid >> 2;                 // 0..127 (row within q-block)
  const unsigned short* aSrc[2];
#pragma unroll
  for (int q = 0; q < 2; ++q)
    aSrc[q] = A + (size_t)(bm + q * 128 + srow) * DD + k16s * 8;
  const unsigned short* bSrc = Bt + (size_t)(bn + srow) * DD + k16s * 8;

  auto stage = [&](int buf, int kt) {
    unsigned short* ab = lds + buf * 12288;
    unsigned short* bb = ab + 8192;
    const size_t ko = (size_t)kt * 32;
#pragma unroll
    for (int q = 0; q < 2; ++q)
      gl_lds16(aSrc[q] + ko, ab + ((q * 512 + tid) << 3));
    gl_lds16(bSrc + ko, bb + (tid << 3));
  };

  // frag-read swizzled slot offset (elements): phys = g ^ ((r>>1)&3)
  // ((R>>1)&3 with R = wm*64 + mi*16 + r reduces to (r>>1)&3: mi*8, wm*32
  // are multiples of 4). 8 lanes per 16B bank-group -> conflict-free b128.
  const int sa = (g ^ ((r >> 1) & 3)) * 8;
  const int arow0 = wm * 64 + r;
  const int brow0 = wn * 64 + r;

  f32x4 acc[4][4] = {};
  stage(0, 0);
  stage(1, 1);
  asm volatile("s_waitcnt vmcnt(3)" ::: "memory");  // tile0 landed (per wave)
  __builtin_amdgcn_s_barrier();

  for (int kt = 0; kt < DD / 32; ++kt) {
    const int cur = kt % 3;
    if (kt + 2 < DD / 32) stage((kt + 2) % 3, kt + 2);
    const unsigned short* ab = lds + cur * 12288;
    const unsigned short* bb = ab + 8192;
    bf16x8 af[4], bfr[4];
#pragma unroll
    for (int mi = 0; mi < 4; ++mi)
      af[mi] = *(const bf16x8*)(ab + (arow0 + mi * 16) * 32 + sa);
#pragma unroll
    for (int ni = 0; ni < 4; ++ni)
      bfr[ni] = *(const bf16x8*)(bb + (brow0 + ni * 16) * 32 + sa);
    __builtin_amdgcn_s_setprio(1);
#pragma unroll
    for (int mi = 0; mi < 4; ++mi)
#pragma unroll
      for (int ni = 0; ni < 4; ++ni)
        acc[mi][ni] = __builtin_amdgcn_mfma_f32_16x16x32_bf16(af[mi], bfr[ni], acc[mi][ni], 0, 0, 0);
    __builtin_amdgcn_s_setprio(0);
    if (kt < DD / 32 - 2) {
      asm volatile("s_waitcnt vmcnt(3)" ::: "memory");  // tile kt+1 landed
    } else {
      asm volatile("s_waitcnt vmcnt(0)" ::: "memory");  // tail drain
    }
    __builtin_amdgcn_s_barrier();
  }

  // ---- fused epilogue: bias + tanh -> bf16 T, per-row partial LN sums ----
  float bv[4];
#pragma unroll
  for (int ni = 0; ni < 4; ++ni) bv[ni] = bias[bn + wn * 64 + ni * 16 + r];
  const int slot = ((lin & 15) << 1) + wn;  // 32 col-groups of 64
#pragma unroll
  for (int mi = 0; mi < 4; ++mi) {
#pragma unroll
    for (int i2 = 0; i2 < 4; ++i2) {
      const int row = bm + wm * 64 + mi * 16 + g * 4 + i2;
      unsigned short* trow = T + (size_t)row * DD + bn + wn * 64 + r;
      float s1 = 0.f, s2 = 0.f;
#pragma unroll
      for (int ni = 0; ni < 4; ++ni) {
        const float tv = tanhf(acc[mi][ni][i2] + bv[ni]);
        trow[ni * 16] = f2bf(tv);
        s1 += tv;
        s2 += tv * tv;
      }
#pragma unroll
      for (int m = 1; m < 16; m <<= 1) {
        s1 += __shfl_xor(s1, m, 64);
        s2 += __shfl_xor(s2, m, 64);
      }
      if (r == 0) {
        float2 p2 = make_float2(s1, s2);
        *(float2*)(part + (size_t)row * 64 + slot * 2) = p2;
      }
    }
  }
}

// --------------------------------------------------------------------------
// part[row][32][2] -> stats[row] = (mean, rstd). One 32-lane group per row.
// grid = MO/8, block 256.
// --------------------------------------------------------------------------
__global__ __launch_bounds__(256) void k_stats(const float* __restrict__ part,
                                               float2* __restrict__ stats) {
  const int t = threadIdx.x;
  const int row = blockIdx.x * 8 + (t >> 5);
  const int i = t & 31;
  float2 p = ((const float2*)(part + (size_t)row * 64))[i];
  float s1 = p.x, s2 = p.y;
#pragma unroll
  for (int m = 1; m < 32; m <<= 1) {
    s1 += __shfl_xor(s1, m, 64);
    s2 += __shfl_xor(s2, m, 64);
  }
  if (i == 0) {
    const float mean = s1 * (1.0f / DD);
    const float var = s2 * (1.0f / DD) - mean * mean;
    stats[row] = make_float2(mean, rsqrtf(var + 1e-5f));
  }
}

// --------------------------------------------------------------------------
// Fused LN + dual-layout write: o = (T - mean)*rstd*g + b (bf16);
// writes oe[b][n][d] (row-major) AND oeT[b][d][n] (LDS transpose).
// grid (36, 32, 8), block 256.
// --------------------------------------------------------------------------
__global__ __launch_bounds__(256) void k_lnT(const unsigned short* __restrict__ T,
                                             const float2* __restrict__ stats,
                                             const float* __restrict__ gw,
                                             const float* __restrict__ bw,
                                             unsigned short* __restrict__ oe,
                                             unsigned short* __restrict__ oeT) {
  __shared__ unsigned short sh[64][65];
  const int t = threadIdx.x;
  const int b = blockIdx.z, nt = blockIdx.x, dt = blockIdx.y;
  {
    const int nn = t >> 2, seg = t & 3;
    const int row = b * NOBJ + nt * 64 + nn;
    const size_t base = (size_t)row * DD + dt * 64 + seg * 16;
    u32x4 x0 = ((const u32x4*)(T + base))[0];
    u32x4 x1 = ((const u32x4*)(T + base))[1];
    const float2 st = stats[row];
    const float* gp = gw + dt * 64 + seg * 16;
    const float* bp = bw + dt * 64 + seg * 16;
    f32x4 gq[4], bq[4];
#pragma unroll
    for (int q = 0; q < 4; ++q) {
      gq[q] = ((const f32x4*)gp)[q];
      bq[q] = ((const f32x4*)bp)[q];
    }
    const unsigned short* px0 = (const unsigned short*)&x0;
    const unsigned short* px1 = (const unsigned short*)&x1;
    unsigned short ov[16];
#pragma unroll
    for (int j = 0; j < 8; ++j) {
      const float v = bf2f(px0[j]);
      ov[j] = f2bf((v - st.x) * st.y * gq[j >> 2][j & 3] + bq[j >> 2][j & 3]);
    }
#pragma unroll
    for (int j = 0; j < 8; ++j) {
      const float v = bf2f(px1[j]);
      ov[8 + j] = f2bf((v - st.x) * st.y * gq[2 + (j >> 2)][j & 3] + bq[2 + (j >> 2)][j & 3]);
    }
    u32x4 o0 = {(unsigned int)ov[0] | ((unsigned int)ov[1] << 16),
                (unsigned int)ov[2] | ((unsigned int)ov[3] << 16),
                (unsigned int)ov[4] | ((unsigned int)ov[5] << 16),
                (unsigned int)ov[6] | ((unsigned int)ov[7] << 16)};
    u32x4 o1 = {(unsigned int)ov[8] | ((unsigned int)ov[9] << 16),
                (unsigned int)ov[10] | ((unsigned int)ov[11] << 16),
                (unsigned int)ov[12] | ((unsigned int)ov[13] << 16),
                (unsigned int)ov[14] | ((unsigned int)ov[15] << 16)};
    ((u32x4*)(oe + base))[0] = o0;
    ((u32x4*)(oe + base))[1] = o1;
#pragma unroll
    for (int j = 0; j < 16; ++j) sh[nn][seg * 16 + j] = ov[j];
  }
  __syncthreads();
  {
    const int dd = t >> 2, ns = t & 3;
    unsigned int o[8];
#pragma unroll
    for (int j = 0; j < 8; ++j)
      o[j] = (unsigned int)sh[ns * 16 + 2 * j][dd] |
             ((unsigned int)sh[ns * 16 + 2 * j + 1][dd] << 16);
    u32x4 p0 = {o[0], o[1], o[2], o[3]};
    u32x4 p1 = {o[4], o[5], o[6], o[7]};
    unsigned short* dst = oeT + ((size_t)b * DD + dt * 64 + dd) * NOBJ + nt * 64 + ns * 16;
    ((u32x4*)dst)[0] = p0;
    ((u32x4*)dst)[1] = p1;
  }
}

// --------------------------------------------------------------------------
// Y[M][2048] = X[M][2048](fp32) @ W + bias (inline convert). Visual branch.
// --------------------------------------------------------------------------
__global__ __launch_bounds__(256) void k_gemm_xw(const float* __restrict__ X,
                                                 const unsigned short* __restrict__ Wt,
                                                 const float* __restrict__ bias,
                                                 float* __restrict__ Y) {
  __shared__ __align__(16) unsigned short As[128 * 32];
  __shared__ __align__(16) unsigned short Bs[128 * 32];
  const int t = threadIdx.x;
  const int lane = t & 63, wave = t >> 6;
  const int r = lane & 15, g = lane >> 4;
  const int wm = wave >> 1, wn = wave & 1;
  const int bm = blockIdx.y * 128, bn = blockIdx.x * 128;
  const int arow = t >> 1, ah = t & 1;
  f32x4 acc[4][4] = {};
  const float* aptr = X + (size_t)(bm + arow) * DD + ah * 16;
  const unsigned short* bptr = Wt + (size_t)(bn + arow) * DD + ah * 16;
  for (int kt = 0; kt < DD / 32; ++kt) {
    const int kb = kt * 32;
    f32x4 a0 = *(const f32x4*)(aptr + kb);
    f32x4 a1 = *(const f32x4*)(aptr + kb + 4);
    f32x4 a2 = *(const f32x4*)(aptr + kb + 8);
    f32x4 a3 = *(const f32x4*)(aptr + kb + 12);
    u32x4 b0 = *(const u32x4*)(bptr + kb);
    u32x4 b1 = *(const u32x4*)(bptr + kb + 8);
    __syncthreads();
    u32x4 p0 = {pk2(a0.x, a0.y), pk2(a0.z, a0.w), pk2(a1.x, a1.y), pk2(a1.z, a1.w)};
    u32x4 p1 = {pk2(a2.x, a2.y), pk2(a2.z, a2.w), pk2(a3.x, a3.y), pk2(a3.z, a3.w)};
    ((u32x4*)As)[arow * 4 + ah * 2 + 0] = p0;
    ((u32x4*)As)[arow * 4 + ah * 2 + 1] = p1;
    ((u32x4*)Bs)[arow * 4 + ah * 2 + 0] = b0;
    ((u32x4*)Bs)[arow * 4 + ah * 2 + 1] = b1;
    __syncthreads();
    bf16x8 af[4], bfr[4];
#pragma unroll
    for (int m = 0; m < 4; ++m) af[m] = ((const bf16x8*)As)[(wm * 64 + m * 16 + r) * 4 + g];
#pragma unroll
    for (int n = 0; n < 4; ++n) bfr[n] = ((const bf16x8*)Bs)[(wn * 64 + n * 16 + r) * 4 + g];
#pragma unroll
    for (int m = 0; m < 4; ++m)
#pragma unroll
      for (int n = 0; n < 4; ++n)
        acc[m][n] = __builtin_amdgcn_mfma_f32_16x16x32_bf16(af[m], bfr[n], acc[m][n], 0, 0, 0);
  }
#pragma unroll
  for (int m = 0; m < 4; ++m) {
    const int row0 = bm + wm * 64 + m * 16 + g * 4;
#pragma unroll
    for (int n = 0; n < 4; ++n) {
      const int col = bn + wn * 64 + n * 16 + r;
      const float bvx = bias[col];
#pragma unroll
      for (int i = 0; i < 4; ++i)
        Y[(size_t)(row0 + i) * DD + col] = acc[m][n][i] + bvx;
    }
  }
}

// --------------------------------------------------------------------------
// Row-wise: t = tanh(Y[row] (+ Y2[row])); LN(t)*g+b -> optional bf16 / fp32.
// --------------------------------------------------------------------------
__global__ __launch_bounds__(256) void k_ep_ln(const float* __restrict__ Y,
                                               const float* __restrict__ Y2,
                                               const float* __restrict__ gw,
                                               const float* __restrict__ bw,
                                               unsigned short* __restrict__ obf,
                                               float* __restrict__ of32) {
  const int row = blockIdx.x, t = threadIdx.x;
  const size_t base = (size_t)row * DD + t * 8;
  f32x4 v0 = ((const f32x4*)(Y + base))[0];
  f32x4 v1 = ((const f32x4*)(Y + base))[1];
  if (Y2 != nullptr) {
    v0 += ((const f32x4*)(Y2 + base))[0];
    v1 += ((const f32x4*)(Y2 + base))[1];
  }
  float tv[8];
#pragma unroll
  for (int j = 0; j < 4; ++j) {
    tv[j] = tanhf(v0[j]);
    tv[4 + j] = tanhf(v1[j]);
  }
  float s1 = 0.f, s2 = 0.f;
#pragma unroll
  for (int j = 0; j < 8; ++j) {
    s1 += tv[j];
    s2 += tv[j] * tv[j];
  }
#pragma unroll
  for (int m = 1; m < 64; m <<= 1) {
    s1 += __shfl_xor(s1, m, 64);
    s2 += __shfl_xor(s2, m, 64);
  }
  __shared__ float r1[4], r2[4];
  const int wave = t >> 6;
  if ((t & 63) == 0) {
    r1[wave] = s1;
    r2[wave] = s2;
  }
  __syncthreads();
  const float S1 = r1[0] + r1[1] + r1[2] + r1[3];
  const float S2 = r2[0] + r2[1] + r2[2] + r2[3];
  const float mean = S1 * (1.0f / DD);
  const float var = S2 * (1.0f / DD) - mean * mean;
  const float rstd = rsqrtf(var + 1e-5f);
  f32x4 g0 = ((const f32x4*)(gw + t * 8))[0], g1 = ((const f32x4*)(gw + t * 8))[1];
  f32x4 bb0 = ((const f32x4*)(bw + t * 8))[0], bb1 = ((const f32x4*)(bw + t * 8))[1];
  float o[8];
#pragma unroll
  for (int j = 0; j < 4; ++j) {
    o[j] = (tv[j] - mean) * rstd * g0[j] + bb0[j];
    o[4 + j] = (tv[4 + j] - mean) * rstd * g1[j] + bb1[j];
  }
  if (obf != nullptr) {
    u32x4 p = {pk2(o[0], o[1]), pk2(o[2], o[3]), pk2(o[4], o[5]), pk2(o[6], o[7])};
    *((u32x4*)(obf + base)) = p;
  }
  if (of32 != nullptr) {
    f32x4 w0 = {o[0], o[1], o[2], o[3]}, w1 = {o[4], o[5], o[6], o[7]};
    ((f32x4*)(of32 + base))[0] = w0;
    ((f32x4*)(of32 + base))[1] = w1;
  }
}

// --------------------------------------------------------------------------
// adjT[b][f][n] = (oe[b][n][:] . ve[b][f][:]) / sqrt(2048).
// BM=64(n), 256 thr 4 waves. grid (36, 8) = 288 blocks.
// --------------------------------------------------------------------------
__global__ __launch_bounds__(256) void k_gemm_adj(const unsigned short* __restrict__ oe,
                                                  const unsigned short* __restrict__ veb,
                                                  float* __restrict__ adjT) {
  __shared__ __align__(16) unsigned short As[64 * 32];
  __shared__ __align__(16) unsigned short Bs[64 * 32];
  const int t = threadIdx.x;
  const int lane = t & 63, wave = t >> 6;
  const int r = lane & 15, g = lane >> 4;
  const int wm = wave >> 1, wn = wave & 1;
  const int b = blockIdx.y, bm = blockIdx.x * 64;
  const int arow = t >> 2, aseg = t & 3;
  f32x4 acc[2][2] = {};
  const unsigned short* aptr = oe + ((size_t)b * NOBJ + bm + arow) * DD + aseg * 8;
  const unsigned short* bptr = veb + ((size_t)b * FF + arow) * DD + aseg * 8;
  for (int kt = 0; kt < DD / 32; ++kt) {
    const int kb = kt * 32;
    u32x4 a0 = *(const u32x4*)(aptr + kb);
    u32x4 bvx = *(const u32x4*)(bptr + kb);
    __syncthreads();
    ((u32x4*)As)[arow * 4 + aseg] = a0;
    ((u32x4*)Bs)[arow * 4 + aseg] = bvx;
    __syncthreads();
    bf16x8 af[2], bfr[2];
#pragma unroll
    for (int m = 0; m < 2; ++m) af[m] = ((const bf16x8*)As)[(wm * 32 + m * 16 + r) * 4 + g];
#pragma unroll
    for (int n = 0; n < 2; ++n) bfr[n] = ((const bf16x8*)Bs)[(wn * 32 + n * 16 + r) * 4 + g];
#pragma unroll
    for (int m = 0; m < 2; ++m)
#pragma unroll
      for (int n = 0; n < 2; ++n)
        acc[m][n] = __builtin_amdgcn_mfma_f32_16x16x32_bf16(af[m], bfr[n], acc[m][n], 0, 0, 0);
  }
  const float scale = 0.02209708691207961f;  // 1/sqrt(2048)
#pragma unroll
  for (int m = 0; m < 2; ++m)
#pragma unroll
    for (int n = 0; n < 2; ++n) {
      const int f = wn * 32 + n * 16 + r;
      const int n0 = bm + wm * 32 + m * 16 + g * 4;
      f32x4 v = acc[m][n];
      v *= scale;
      *(f32x4*)(adjT + ((size_t)b * FF + f) * NOBJ + n0) = v;
    }
}

// --------------------------------------------------------------------------
// Row softmax over 2304 (rows of adjT), write bf16. grid = 512 rows.
// --------------------------------------------------------------------------
__global__ __launch_bounds__(256) void k_smax(const float* __restrict__ adjT,
                                              unsigned short* __restrict__ out) {
  const int t = threadIdx.x;
  const size_t base = (size_t)blockIdx.x * NOBJ;
  float v[9];
#pragma unroll
  for (int j = 0; j < 9; ++j) v[j] = adjT[base + t + j * 256];
  float m = v[0];
#pragma unroll
  for (int j = 1; j < 9; ++j) m = fmaxf(m, v[j]);
#pragma unroll
  for (int s = 1; s < 64; s <<= 1) m = fmaxf(m, __shfl_xor(m, s, 64));
  __shared__ float rm[4], rs[4];
  const int wave = t >> 6;
  if ((t & 63) == 0) rm[wave] = m;
  __syncthreads();
  m = fmaxf(fmaxf(rm[0], rm[1]), fmaxf(rm[2], rm[3]));
  float e[9];
  float s = 0.f;
#pragma unroll
  for (int j = 0; j < 9; ++j) {
    e[j] = __expf(v[j] - m);
    s += e[j];
  }
#pragma unroll
  for (int q = 1; q < 64; q <<= 1) s += __shfl_xor(s, q, 64);
  if ((t & 63) == 0) rs[wave] = s;
  __syncthreads();
  const float S = rs[0] + rs[1] + rs[2] + rs[3];
  const float inv = 1.0f / S;
#pragma unroll
  for (int j = 0; j < 9; ++j) out[base + t + j * 256] = f2bf(e[j] * inv);
}

// --------------------------------------------------------------------------
// agg[b][f][d] = sum_n adj_sm[b][f][n] * oeT[b][d][n].
// BN=64(d), 256 thr 4 waves. grid (32, 8) = 256 blocks.
// --------------------------------------------------------------------------
__global__ __launch_bounds__(256) void k_gemm_agg(const unsigned short* __restrict__ adjsm,
                                                  const unsigned short* __restrict__ oeT,
                                                  float* __restrict__ agg) {
  __shared__ __align__(16) unsigned short As[64 * 32];
  __shared__ __align__(16) unsigned short Bs[64 * 32];
  const int t = threadIdx.x;
  const int lane = t & 63, wave = t >> 6;
  const int r = lane & 15, g = lane >> 4;
  const int wm = wave >> 1, wn = wave & 1;
  const int b = blockIdx.y, bn = blockIdx.x * 64;
  const int arow = t >> 2, aseg = t & 3;
  f32x4 acc[2][2] = {};
  const unsigned short* aptr = adjsm + ((size_t)b * FF + arow) * NOBJ + aseg * 8;
  const unsigned short* bptr = oeT + ((size_t)b * DD + bn + arow) * NOBJ + aseg * 8;
  for (int kt = 0; kt < NOBJ / 32; ++kt) {
    const int kb = kt * 32;
    u32x4 av = *(const u32x4*)(aptr + kb);
    u32x4 bvx = *(const u32x4*)(bptr + kb);
    __syncthreads();
    ((u32x4*)As)[arow * 4 + aseg] = av;
    ((u32x4*)Bs)[arow * 4 + aseg] = bvx;
    __syncthreads();
    bf16x8 af[2], bfr[2];
#pragma unroll
    for (int m = 0; m < 2; ++m) af[m] = ((const bf16x8*)As)[(wm * 32 + m * 16 + r) * 4 + g];
#pragma unroll
    for (int n = 0; n < 2; ++n) bfr[n] = ((const bf16x8*)Bs)[(wn * 32 + n * 16 + r) * 4 + g];
#pragma unroll
    for (int m = 0; m < 2; ++m)
#pragma unroll
      for (int n = 0; n < 2; ++n)
        acc[m][n] = __builtin_amdgcn_mfma_f32_16x16x32_bf16(af[m], bfr[n], acc[m][n], 0, 0, 0);
  }
#pragma unroll
  for (int m = 0; m < 2; ++m)
#pragma unroll
    for (int n = 0; n < 2; ++n) {
      const int d = bn + wn * 32 + n * 16 + r;
#pragma unroll
      for (int i = 0; i < 4; ++i) {
        const int f = wm * 32 + m * 16 + g * 4 + i;
        agg[((size_t)b * FF + f) * DD + d] = acc[m][n][i];
      }
    }
}

// --------------------------------------------------------------------------

extern "C" void kernel_launch(void* const* d_in, const int* in_sizes, int n_in,
                              void* d_out, int out_size, void* d_ws, size_t ws_size,
                              hipStream_t stream) {
  (void)in_sizes; (void)n_in; (void)out_size;
  const float* visual = (const float*)d_in[0];
  const float* obj    = (const float*)d_in[1];
  const float* W_v    = (const float*)d_in[2];
  const float* b_v    = (const float*)d_in[3];
  const float* W_o    = (const float*)d_in[4];
  const float* b_o    = (const float*)d_in[5];
  const float* ln_v_g = (const float*)d_in[6];
  const float* ln_v_b = (const float*)d_in[7];
  const float* ln_o_g = (const float*)d_in[8];
  const float* ln_o_b = (const float*)d_in[9];
  const float* ln_ov_g = (const float*)d_in[10];
  const float* ln_ov_b = (const float*)d_in[11];

  // Workspace layout (248 MiB; aliases annotated with lifetimes):
  //   [0,8M)      WvT (dead after gemm_xw)      -> adjT @0 (4.5M), adjs @5M
  //   [8M,16M)    WoT (dead after gemm_bbf)     -> agg @8M (4M)
  //   [16M,88M)   objb (dead after gemm_bbf)    -> oeT (written by k_lnT)
  //   [88M,160M)  T (bf16 tanh; read by k_lnT)
  //   [160M,165M) part
  //   [165M,166M) stats
  //   [166M,170M) Yv
  //   [170M,174M) ve_f
  //   [174M,176M) ve_b
  //   [176M,248M) oe_b
  char* ws = (char*)d_ws;
  constexpr size_t OFF_WVT  = 0;
  constexpr size_t OFF_ADJ  = 0;                  // alias (WvT dead)
  constexpr size_t OFF_ADJS = 5ull << 20;         // alias (WvT dead)
  constexpr size_t OFF_WOT  = 8ull << 20;
  constexpr size_t OFF_AGG  = 8ull << 20;         // alias (WoT dead)
  constexpr size_t OFF_OBJB = 16ull << 20;
  constexpr size_t OFF_OET  = 16ull << 20;        // alias (objb dead)
  constexpr size_t OFF_T    = 88ull << 20;
  constexpr size_t OFF_PART = 160ull << 20;
  constexpr size_t OFF_STAT = 165ull << 20;
  constexpr size_t OFF_YV   = 166ull << 20;
  constexpr size_t OFF_VEF  = 170ull << 20;
  constexpr size_t OFF_VEB  = 174ull << 20;
  constexpr size_t OFF_OEB  = 176ull << 20;
  constexpr size_t WS_NEED  = 248ull << 20;
  if (ws_size < WS_NEED) return;

  unsigned short* WvT  = (unsigned short*)(ws + OFF_WVT);
  unsigned short* WoT  = (unsigned short*)(ws + OFF_WOT);
  unsigned short* objb = (unsigned short*)(ws + OFF_OBJB);
  unsigned short* oeT  = (unsigned short*)(ws + OFF_OET);
  unsigned short* T    = (unsigned short*)(ws + OFF_T);
  float* part          = (float*)(ws + OFF_PART);
  float2* stats        = (float2*)(ws + OFF_STAT);
  float* Yv            = (float*)(ws + OFF_YV);
  float* ve_f          = (float*)(ws + OFF_VEF);
  unsigned short* ve_b = (unsigned short*)(ws + OFF_VEB);
  unsigned short* oe_b = (unsigned short*)(ws + OFF_OEB);
  float* adjT          = (float*)(ws + OFF_ADJ);
  unsigned short* adjs = (unsigned short*)(ws + OFF_ADJS);
  float* agg           = (float*)(ws + OFF_AGG);

  dim3 b256(256);
  // 1) weight transpose+convert (both), obj fp32->bf16
  k_wprep2<<<dim3(32, 32, 2), b256, 0, stream>>>(W_v, W_o, WvT, WoT);
  k_cvt_bf16<<<dim3(2048), b256, 0, stream>>>(obj, objb, MO * DD / 16);
  // 2) branch GEMMs (obj GEMM fused with tanh + LN partials)
  k_gemm_xw<<<dim3(16, MV / 128), b256, 0, stream>>>(visual, WvT, b_v, Yv);
  k_gemm_bbf<<<dim3(16, MO / 256), dim3(512), 0, stream>>>(objb, WoT, b_o, T, part);
  // 3) LN finish: visual row-wise; obj stats + fused LN/transpose
  k_ep_ln<<<dim3(MV), b256, 0, stream>>>(Yv, nullptr, ln_v_g, ln_v_b, ve_b, ve_f);
  k_stats<<<dim3(MO / 8), b256, 0, stream>>>(part, stats);
  k_lnT<<<dim3(36, 32, 8), b256, 0, stream>>>(T, stats, ln_o_g, ln_o_b, oe_b, oeT);
  // 4) adjacency + softmax
  k_gemm_adj<<<dim3(NOBJ / 64, BS), b256, 0, stream>>>(oe_b, ve_b, adjT);
  k_smax<<<dim3(MV), b256, 0, stream>>>(adjT, adjs);
  // 5) aggregation
  k_gemm_agg<<<dim3(DD / 64, BS), b256, 0, stream>>>(adjs, oeT, agg);
  // 6) final add + tanh + LN -> d_out (fp32)
  k_ep_ln<<<dim3(MV), b256, 0, stream>>>(agg, ve_f, ln_ov_g, ln_ov_b, nullptr, (float*)d_out);
}